// Round 1
// baseline (680.388 us; speedup 1.0000x reference)
//
#include <hip/hip_runtime.h>

// ---------- types ----------
typedef __attribute__((ext_vector_type(8))) short short8;
typedef __attribute__((ext_vector_type(4))) short short4v;
typedef __attribute__((ext_vector_type(4))) float f32x4;

static __device__ __forceinline__ short f2bf(float x) {
    unsigned u = __builtin_bit_cast(unsigned, x);
    unsigned r = (u + 0x7fffu + ((u >> 16) & 1u)) >> 16;
    return (short)r;
}

#define QL 512
#define VL 2048
#define DM 1024
#define NH 8
#define DH 128
#define NB 8
#define KQ 1088   // 1024 + 64 (U columns padded)

// ---------- tiny prep kernels ----------
__global__ void cbias_k(const float* __restrict__ bq, const float* __restrict__ bu,
                        const float* __restrict__ bias, float* __restrict__ cbias) {
    int i = blockIdx.x * 256 + threadIdx.x;
    if (i < DM) cbias[i] = bq[i] + bu[i] + bias[i];
}

// conv1d over last_align -> bf16 into Aq[:, 1024:1088] (cols 1034..1087 zero)
__global__ void conv_prep_k(const float* __restrict__ la, const float* __restrict__ cw,
                            const float* __restrict__ cb, short* __restrict__ Aq) {
    int m = blockIdx.x * 256 + threadIdx.x;      // 0..4095
    if (m >= NB * QL) return;
    int b = m >> 9, t = m & 511;
    const float* l = la + b * QL;
    float lm = (t > 0)      ? l[t - 1] : 0.f;
    float l0 = l[t];
    float lp = (t < QL - 1) ? l[t + 1] : 0.f;
    short* row = Aq + (size_t)m * KQ + 1024;
#pragma unroll
    for (int k = 0; k < 10; ++k)
        row[k] = f2bf(cb[k] + lm * cw[k * 3 + 0] + l0 * cw[k * 3 + 1] + lp * cw[k * 3 + 2]);
    for (int k = 10; k < 64; ++k) row[k] = 0;
}

// cast Q -> Aq[:, 0:1024] and combined[:, 1024:2048]
__global__ void castq_k(const float* __restrict__ Q, short* __restrict__ Aq,
                        short* __restrict__ comb) {
    int id = blockIdx.x * 256 + threadIdx.x;     // 0..524287
    int m = id >> 7, kc = (id & 127) * 8;
    const float* p = Q + (size_t)m * DM + kc;
    float4 f0 = *(const float4*)p;
    float4 f1 = *(const float4*)(p + 4);
    short8 v;
    v[0]=f2bf(f0.x); v[1]=f2bf(f0.y); v[2]=f2bf(f0.z); v[3]=f2bf(f0.w);
    v[4]=f2bf(f1.x); v[5]=f2bf(f1.y); v[6]=f2bf(f1.z); v[7]=f2bf(f1.w);
    *(short8*)(Aq + (size_t)m * KQ + kc) = v;
    *(short8*)(comb + (size_t)m * (2 * DM) + DM + kc) = v;
}

// cast weights: Bq = [Wq | Wu | 0], Bv = Wv, Bfc = fc_w  (all bf16, N x K row-major)
__global__ void buildw_k(const float* __restrict__ Wq, const float* __restrict__ Wu,
                         const float* __restrict__ Wv, const float* __restrict__ fcw,
                         short* __restrict__ Bq, short* __restrict__ Bv, short* __restrict__ Bfc) {
    int id = blockIdx.x * 256 + threadIdx.x;
    const int nq = DM * KQ;             // 1024*1088
    const int nv = DM * DM;             // 1024*1024
    const int nf = DM * 2 * DM;         // 1024*2048
    if (id < nq) {
        int n = id / KQ, k = id % KQ;
        float v = (k < 1024) ? Wq[(size_t)n * 1024 + k]
                             : ((k < 1034) ? Wu[n * 10 + (k - 1024)] : 0.f);
        Bq[id] = f2bf(v);
    } else if (id < nq + nv) {
        int j = id - nq;
        Bv[j] = f2bf(Wv[j]);
    } else if (id < nq + nv + nf) {
        int j = id - nq - nv;
        Bfc[j] = f2bf(fcw[j]);
    }
}

// ---------- generic MFMA GEMM: C[m][n] = sum_k A[m][k]*B[n][k] (+bias epilogues) ----------
// MODE 0: v_s  — bf16 out (out_ld) + transposed bf16 out vT[(b*8+h)*128+hd][v]
// MODE 1: q_s  — bf16 out
// MODE 2: fc   — f32 out = tanh(val + bias)
template <typename AT, int MODE>
__global__ __launch_bounds__(256) void gemm_k(
    const AT* __restrict__ A, const short* __restrict__ B,
    const float* __restrict__ bias, void* __restrict__ out0,
    short* __restrict__ outT, int M, int N, int K, int out_ld) {
    __shared__ short As[128][72];
    __shared__ short Bs[128][72];
    const int tid = threadIdx.x;
    const int lane = tid & 63, wave = tid >> 6;
    const int g = lane >> 4, c = lane & 15;
    const int nbm = M >> 7;
    const int bm = blockIdx.x % nbm, bn = blockIdx.x / nbm;
    const int wr = wave >> 1, wc = wave & 1;

    // staging pointers (4 chunks of 8 elems per thread per operand)
    const AT* aptr[4];
    const short* bptr[4];
    short* asl[4];
    short* bsl[4];
#pragma unroll
    for (int i = 0; i < 4; ++i) {
        int id = tid * 4 + i;           // 0..1023
        int row = id >> 3;              // 0..127
        int kc = (id & 7) * 8;          // 0..56
        aptr[i] = A + (size_t)(bm * 128 + row) * K + kc;
        bptr[i] = B + (size_t)(bn * 128 + row) * K + kc;
        asl[i] = &As[row][kc];
        bsl[i] = &Bs[row][kc];
    }

    f32x4 acc[4][4] = {};

    for (int k0 = 0; k0 < K; k0 += 64) {
        __syncthreads();
#pragma unroll
        for (int i = 0; i < 4; ++i) {
            short8 av;
            if constexpr (sizeof(AT) == 4) {
                const float* ap = (const float*)(aptr[i]) + k0;
                float4 f0 = *(const float4*)ap;
                float4 f1 = *(const float4*)(ap + 4);
                av[0]=f2bf(f0.x); av[1]=f2bf(f0.y); av[2]=f2bf(f0.z); av[3]=f2bf(f0.w);
                av[4]=f2bf(f1.x); av[5]=f2bf(f1.y); av[6]=f2bf(f1.z); av[7]=f2bf(f1.w);
            } else {
                av = *(const short8*)((const short*)(aptr[i]) + k0);
            }
            *(short8*)asl[i] = av;
            *(short8*)bsl[i] = *(const short8*)(bptr[i] + k0);
        }
        __syncthreads();
#pragma unroll
        for (int ks = 0; ks < 2; ++ks) {
            short8 af[4], bfr[4];
#pragma unroll
            for (int mi = 0; mi < 4; ++mi) af[mi] = *(short8*)&As[wr * 64 + mi * 16 + c][ks * 32 + g * 8];
#pragma unroll
            for (int ni = 0; ni < 4; ++ni) bfr[ni] = *(short8*)&Bs[wc * 64 + ni * 16 + c][ks * 32 + g * 8];
#pragma unroll
            for (int mi = 0; mi < 4; ++mi)
#pragma unroll
                for (int ni = 0; ni < 4; ++ni)
                    acc[mi][ni] = __builtin_amdgcn_mfma_f32_16x16x32_bf16(af[mi], bfr[ni], acc[mi][ni], 0, 0, 0);
        }
    }

    const int m0 = bm * 128 + wr * 64, n0 = bn * 128 + wc * 64;
#pragma unroll
    for (int ni = 0; ni < 4; ++ni) {
        int n = n0 + ni * 16 + c;
        float bn_ = bias[n];
#pragma unroll
        for (int mi = 0; mi < 4; ++mi) {
            int mb = m0 + mi * 16 + 4 * g;
            f32x4 v = acc[mi][ni];
            if constexpr (MODE == 2) {
                float* o = (float*)out0;
#pragma unroll
                for (int r = 0; r < 4; ++r)
                    o[(size_t)(mb + r) * out_ld + n] = tanhf(v[r] + bn_);
            } else {
                short* o = (short*)out0;
                short4v pk;
#pragma unroll
                for (int r = 0; r < 4; ++r) {
                    pk[r] = f2bf(v[r] + bn_);
                    o[(size_t)(mb + r) * out_ld + n] = pk[r];
                }
                if constexpr (MODE == 0) {
                    int h = n >> 7, hd = n & 127;
                    int bb = mb >> 11, vv = mb & 2047;
                    *(short4v*)(outT + ((size_t)((bb * NH + h) * DH + hd)) * VL + vv) = pk;
                }
            }
        }
    }
}

// ---------- attention: sigmoid-normalized, two-pass (rowsum then align+PV) ----------
__global__ __launch_bounds__(256) void attn_k(
    const short* __restrict__ qs, const short* __restrict__ vs,
    const short* __restrict__ vsT, float* __restrict__ align_out,
    short* __restrict__ comb) {
    __shared__ short Pl[4][16][72];
    const int blk = blockIdx.x;                 // 0..511
    const int qt = blk & 7, bh = blk >> 3, h = bh & 7, b = bh >> 3;
    const int tid = threadIdx.x, wave = tid >> 6, lane = tid & 63;
    const int g = lane >> 4, c = lane & 15;
    const int q0 = qt * 64 + wave * 16;
    const float sc = 0.08838834764831845f;      // 1/sqrt(128)

    short8 qa[4];
    const short* qb = qs + ((size_t)(b * QL + q0 + c)) * DM + h * DH + g * 8;
#pragma unroll
    for (int ks = 0; ks < 4; ++ks) qa[ks] = *(const short8*)(qb + ks * 32);

    const short* vb0 = vs + ((size_t)(b * VL + c)) * DM + h * DH + g * 8;

    // pass 1: row sums of sigmoid(score)
    float rsum[4] = {0.f, 0.f, 0.f, 0.f};
    for (int v0 = 0; v0 < VL; v0 += 64) {
#pragma unroll
        for (int ni = 0; ni < 4; ++ni) {
            f32x4 s = {0.f, 0.f, 0.f, 0.f};
            const short* vb = vb0 + (size_t)(v0 + ni * 16) * DM;
#pragma unroll
            for (int ks = 0; ks < 4; ++ks)
                s = __builtin_amdgcn_mfma_f32_16x16x32_bf16(qa[ks], *(const short8*)(vb + ks * 32), s, 0, 0, 0);
#pragma unroll
            for (int r = 0; r < 4; ++r)
                rsum[r] += 1.f / (1.f + __expf(-s[r] * sc));
        }
    }
#pragma unroll
    for (int off = 1; off < 16; off <<= 1) {
#pragma unroll
        for (int r = 0; r < 4; ++r) rsum[r] += __shfl_xor(rsum[r], off);
    }
    float inv[4];
#pragma unroll
    for (int r = 0; r < 4; ++r) inv[r] = 1.f / rsum[r];

    // pass 2: recompute S, write align, accumulate context with normalized P
    f32x4 ctx[8] = {};
    float* ao = align_out + ((size_t)((h * NB + b) * QL + q0)) * VL;
    const short* vtb0 = vsT + ((size_t)((b * NH + h) * DH + c)) * VL + g * 8;
    for (int v0 = 0; v0 < VL; v0 += 64) {
#pragma unroll
        for (int ni = 0; ni < 4; ++ni) {
            f32x4 s = {0.f, 0.f, 0.f, 0.f};
            const short* vb = vb0 + (size_t)(v0 + ni * 16) * DM;
#pragma unroll
            for (int ks = 0; ks < 4; ++ks)
                s = __builtin_amdgcn_mfma_f32_16x16x32_bf16(qa[ks], *(const short8*)(vb + ks * 32), s, 0, 0, 0);
#pragma unroll
            for (int r = 0; r < 4; ++r) {
                float p = (1.f / (1.f + __expf(-s[r] * sc))) * inv[r];
                ao[(size_t)(4 * g + r) * VL + v0 + ni * 16 + c] = p;
                Pl[wave][4 * g + r][ni * 16 + c] = f2bf(p);
            }
        }
        short8 pa0 = *(const short8*)&Pl[wave][c][g * 8];
        short8 pa1 = *(const short8*)&Pl[wave][c][32 + g * 8];
#pragma unroll
        for (int df = 0; df < 8; ++df) {
            const short* tb = vtb0 + (size_t)(df * 16) * VL + v0;
            ctx[df] = __builtin_amdgcn_mfma_f32_16x16x32_bf16(pa0, *(const short8*)(tb), ctx[df], 0, 0, 0);
            ctx[df] = __builtin_amdgcn_mfma_f32_16x16x32_bf16(pa1, *(const short8*)(tb + 32), ctx[df], 0, 0, 0);
        }
    }
    // write context (bf16) into combined[:, 0:1024]
#pragma unroll
    for (int df = 0; df < 8; ++df)
#pragma unroll
        for (int r = 0; r < 4; ++r)
            comb[((size_t)(b * QL + q0 + 4 * g + r)) * (2 * DM) + h * DH + df * 16 + c] = f2bf(ctx[df][r]);
}

// ---------- launch ----------
extern "C" void kernel_launch(void* const* d_in, const int* in_sizes, int n_in,
                              void* d_out, int out_size, void* d_ws, size_t ws_size,
                              hipStream_t stream) {
    (void)in_sizes; (void)n_in; (void)out_size; (void)ws_size;
    const float* Q    = (const float*)d_in[0];
    const float* V    = (const float*)d_in[1];
    const float* la   = (const float*)d_in[2];
    const float* cw   = (const float*)d_in[3];
    const float* cb   = (const float*)d_in[4];
    const float* Wq   = (const float*)d_in[5];
    const float* bq   = (const float*)d_in[6];
    const float* Wv   = (const float*)d_in[7];
    const float* bv   = (const float*)d_in[8];
    const float* Wu   = (const float*)d_in[9];
    const float* bu   = (const float*)d_in[10];
    const float* bias = (const float*)d_in[11];
    const float* fcw  = (const float*)d_in[12];
    const float* fcb  = (const float*)d_in[13];

    float* out = (float*)d_out;
    float* align_out = out + (size_t)NB * QL * DM;   // 4,194,304

    char* w = (char*)d_ws;
    short* Aq   = (short*)w; w += (size_t)4096 * KQ * 2;       // 8.9 MB
    short* Bq   = (short*)w; w += (size_t)1024 * KQ * 2;       // 2.2 MB
    short* Bvw  = (short*)w; w += (size_t)1024 * 1024 * 2;     // 2 MB
    short* Bfc  = (short*)w; w += (size_t)1024 * 2048 * 2;     // 4 MB
    short* qsb  = (short*)w; w += (size_t)4096 * 1024 * 2;     // 8 MB
    short* vsb  = (short*)w; w += (size_t)16384 * 1024 * 2;    // 32 MB
    short* vsT  = (short*)w; w += (size_t)16384 * 1024 * 2;    // 32 MB
    short* comb = (short*)w; w += (size_t)4096 * 2048 * 2;     // 16 MB
    float* cbias = (float*)w; w += 1024 * 4;

    cbias_k<<<4, 256, 0, stream>>>(bq, bu, bias, cbias);
    conv_prep_k<<<16, 256, 0, stream>>>(la, cw, cb, Aq);
    castq_k<<<2048, 256, 0, stream>>>(Q, Aq, comb);
    {
        int total = 1024 * KQ + 1024 * 1024 + 1024 * 2048;
        buildw_k<<<(total + 255) / 256, 256, 0, stream>>>(Wq, Wu, Wv, fcw, Bq, Bvw, Bfc);
    }
    // q_s = [Q|U] @ [Wq|Wu]^T + (bq+bu+bias)
    gemm_k<short, 1><<<dim3(32 * 8), 256, 0, stream>>>(Aq, Bq, cbias, qsb, nullptr, 4096, 1024, KQ, 1024);
    // v_s = V @ Wv^T + bv  (+ transposed copy per head)
    gemm_k<float, 0><<<dim3(128 * 8), 256, 0, stream>>>(V, Bvw, bv, vsb, vsT, 16384, 1024, 1024, 1024);
    // attention (writes align to d_out, context into combined[:, :1024])
    attn_k<<<512, 256, 0, stream>>>(qsb, vsb, vsT, align_out, comb);
    // output = tanh(combined @ fc_w^T + fc_b)
    gemm_k<short, 2><<<dim3(32 * 8), 256, 0, stream>>>(comb, Bfc, fcb, out, nullptr, 4096, 1024, 2048, 1024);
}

// Round 2
// 640.680 us; speedup vs baseline: 1.0620x; 1.0620x over previous
//
#include <hip/hip_runtime.h>

// ---------- types ----------
typedef __attribute__((ext_vector_type(8))) short short8;
typedef __attribute__((ext_vector_type(4))) short short4v;
typedef __attribute__((ext_vector_type(4))) float f32x4;

static __device__ __forceinline__ short f2bf(float x) {
    unsigned u = __builtin_bit_cast(unsigned, x);
    unsigned r = (u + 0x7fffu + ((u >> 16) & 1u)) >> 16;
    return (short)r;
}

#define QL 512
#define VL 2048
#define DM 1024
#define NH 8
#define DH 128
#define NB 8
#define KQ 1088   // 1024 + 64 (U columns padded)

// ---------- tiny prep kernels ----------
__global__ void cbias_k(const float* __restrict__ bq, const float* __restrict__ bu,
                        const float* __restrict__ bias, float* __restrict__ cbias) {
    int i = blockIdx.x * 256 + threadIdx.x;
    if (i < DM) cbias[i] = bq[i] + bu[i] + bias[i];
}

// conv1d over last_align -> bf16 into Aq[:, 1024:1088] (cols 1034..1087 zero)
__global__ void conv_prep_k(const float* __restrict__ la, const float* __restrict__ cw,
                            const float* __restrict__ cb, short* __restrict__ Aq) {
    int m = blockIdx.x * 256 + threadIdx.x;      // 0..4095
    if (m >= NB * QL) return;
    int b = m >> 9, t = m & 511;
    const float* l = la + b * QL;
    float lm = (t > 0)      ? l[t - 1] : 0.f;
    float l0 = l[t];
    float lp = (t < QL - 1) ? l[t + 1] : 0.f;
    short* row = Aq + (size_t)m * KQ + 1024;
#pragma unroll
    for (int k = 0; k < 10; ++k)
        row[k] = f2bf(cb[k] + lm * cw[k * 3 + 0] + l0 * cw[k * 3 + 1] + lp * cw[k * 3 + 2]);
    for (int k = 10; k < 64; ++k) row[k] = 0;
}

// cast Q -> Aq[:, 0:1024] and combined[:, 1024:2048]
__global__ void castq_k(const float* __restrict__ Q, short* __restrict__ Aq,
                        short* __restrict__ comb) {
    int id = blockIdx.x * 256 + threadIdx.x;     // 0..524287
    int m = id >> 7, kc = (id & 127) * 8;
    const float* p = Q + (size_t)m * DM + kc;
    float4 f0 = *(const float4*)p;
    float4 f1 = *(const float4*)(p + 4);
    short8 v;
    v[0]=f2bf(f0.x); v[1]=f2bf(f0.y); v[2]=f2bf(f0.z); v[3]=f2bf(f0.w);
    v[4]=f2bf(f1.x); v[5]=f2bf(f1.y); v[6]=f2bf(f1.z); v[7]=f2bf(f1.w);
    *(short8*)(Aq + (size_t)m * KQ + kc) = v;
    *(short8*)(comb + (size_t)m * (2 * DM) + DM + kc) = v;
}

// cast weights: Bq = [Wq | Wu | 0], Bv = Wv, Bfc = fc_w  (all bf16, N x K row-major)
__global__ void buildw_k(const float* __restrict__ Wq, const float* __restrict__ Wu,
                         const float* __restrict__ Wv, const float* __restrict__ fcw,
                         short* __restrict__ Bq, short* __restrict__ Bv, short* __restrict__ Bfc) {
    int id = blockIdx.x * 256 + threadIdx.x;
    const int nq = DM * KQ;             // 1024*1088
    const int nv = DM * DM;             // 1024*1024
    const int nf = DM * 2 * DM;         // 1024*2048
    if (id < nq) {
        int n = id / KQ, k = id % KQ;
        float v = (k < 1024) ? Wq[(size_t)n * 1024 + k]
                             : ((k < 1034) ? Wu[n * 10 + (k - 1024)] : 0.f);
        Bq[id] = f2bf(v);
    } else if (id < nq + nv) {
        int j = id - nq;
        Bv[j] = f2bf(Wv[j]);
    } else if (id < nq + nv + nf) {
        int j = id - nq - nv;
        Bfc[j] = f2bf(fcw[j]);
    }
}

// ---------- generic MFMA GEMM: C[m][n] = sum_k A[m][k]*B[n][k] (+bias epilogues) ----------
// MODE 0: v_s  — bf16 out (out_ld) + transposed bf16 out vT[(b*8+h)*128+hd][v]
// MODE 1: q_s  — bf16 out
// MODE 2: fc   — f32 out = tanh(val + bias)
template <typename AT, int MODE>
__global__ __launch_bounds__(256) void gemm_k(
    const AT* __restrict__ A, const short* __restrict__ B,
    const float* __restrict__ bias, void* __restrict__ out0,
    short* __restrict__ outT, int M, int N, int K, int out_ld) {
    __shared__ short As[128][72];
    __shared__ short Bs[128][72];
    const int tid = threadIdx.x;
    const int lane = tid & 63, wave = tid >> 6;
    const int g = lane >> 4, c = lane & 15;
    const int nbm = M >> 7;
    const int bm = blockIdx.x % nbm, bn = blockIdx.x / nbm;
    const int wr = wave >> 1, wc = wave & 1;

    // staging pointers (4 chunks of 8 elems per thread per operand)
    const AT* aptr[4];
    const short* bptr[4];
    short* asl[4];
    short* bsl[4];
#pragma unroll
    for (int i = 0; i < 4; ++i) {
        int id = tid * 4 + i;           // 0..1023
        int row = id >> 3;              // 0..127
        int kc = (id & 7) * 8;          // 0..56
        aptr[i] = A + (size_t)(bm * 128 + row) * K + kc;
        bptr[i] = B + (size_t)(bn * 128 + row) * K + kc;
        asl[i] = &As[row][kc];
        bsl[i] = &Bs[row][kc];
    }

    f32x4 acc[4][4] = {};

    for (int k0 = 0; k0 < K; k0 += 64) {
        __syncthreads();
#pragma unroll
        for (int i = 0; i < 4; ++i) {
            short8 av;
            if constexpr (sizeof(AT) == 4) {
                const float* ap = (const float*)(aptr[i]) + k0;
                float4 f0 = *(const float4*)ap;
                float4 f1 = *(const float4*)(ap + 4);
                av[0]=f2bf(f0.x); av[1]=f2bf(f0.y); av[2]=f2bf(f0.z); av[3]=f2bf(f0.w);
                av[4]=f2bf(f1.x); av[5]=f2bf(f1.y); av[6]=f2bf(f1.z); av[7]=f2bf(f1.w);
            } else {
                av = *(const short8*)((const short*)(aptr[i]) + k0);
            }
            *(short8*)asl[i] = av;
            *(short8*)bsl[i] = *(const short8*)(bptr[i] + k0);
        }
        __syncthreads();
#pragma unroll
        for (int ks = 0; ks < 2; ++ks) {
            short8 af[4], bfr[4];
#pragma unroll
            for (int mi = 0; mi < 4; ++mi) af[mi] = *(short8*)&As[wr * 64 + mi * 16 + c][ks * 32 + g * 8];
#pragma unroll
            for (int ni = 0; ni < 4; ++ni) bfr[ni] = *(short8*)&Bs[wc * 64 + ni * 16 + c][ks * 32 + g * 8];
#pragma unroll
            for (int mi = 0; mi < 4; ++mi)
#pragma unroll
                for (int ni = 0; ni < 4; ++ni)
                    acc[mi][ni] = __builtin_amdgcn_mfma_f32_16x16x32_bf16(af[mi], bfr[ni], acc[mi][ni], 0, 0, 0);
        }
    }

    const int m0 = bm * 128 + wr * 64, n0 = bn * 128 + wc * 64;
#pragma unroll
    for (int ni = 0; ni < 4; ++ni) {
        int n = n0 + ni * 16 + c;
        float bn_ = bias[n];
#pragma unroll
        for (int mi = 0; mi < 4; ++mi) {
            int mb = m0 + mi * 16 + 4 * g;
            f32x4 v = acc[mi][ni];
            if constexpr (MODE == 2) {
                float* o = (float*)out0;
#pragma unroll
                for (int r = 0; r < 4; ++r)
                    o[(size_t)(mb + r) * out_ld + n] = tanhf(v[r] + bn_);
            } else {
                short* o = (short*)out0;
                short4v pk;
#pragma unroll
                for (int r = 0; r < 4; ++r) {
                    pk[r] = f2bf(v[r] + bn_);
                    o[(size_t)(mb + r) * out_ld + n] = pk[r];
                }
                if constexpr (MODE == 0) {
                    int h = n >> 7, hd = n & 127;
                    int bb = mb >> 11, vv = mb & 2047;
                    *(short4v*)(outT + ((size_t)((bb * NH + h) * DH + hd)) * VL + vv) = pk;
                }
            }
        }
    }
}

// ---------- attention: sigmoid-normalized ----------
// Block = (b, h, 16-q-row group). 4 waves split VL (512 v each).
// Two passes over the wave's own chunk (recompute QK in pass 2).
// Cross-wave: rowsum via LDS, context via LDS f32 atomicAdd.
__global__ __launch_bounds__(256) void attn_k(
    const short* __restrict__ qs, const short* __restrict__ vs,
    const short* __restrict__ vsT, float* __restrict__ align_out,
    short* __restrict__ comb) {
    __shared__ short Pl[4][16][72];
    __shared__ float ctx_lds[16][132];   // padded: g-group stride 528 -> 2-way only
    __shared__ float rs[4][16];

    // XCD-grouping decode: physical blk%8 == bh%8, qg is the fast index.
    const int blk = blockIdx.x;          // 0..2047
    const int xr = blk & 7, t = blk >> 3;
    const int qg = t & 31;               // 0..31  (16-row q group)
    const int bh = ((t >> 5) << 3) + xr; // 0..63
    const int h = bh & 7, b = bh >> 3;

    const int tid = threadIdx.x, wave = tid >> 6, lane = tid & 63;
    const int g = lane >> 4, c = lane & 15;
    const int q0 = qg * 16;
    const int vbase = wave * 512;
    const float sc = 0.08838834764831845f;      // 1/sqrt(128)

    // zero ctx accumulation buffer
    for (int i = tid; i < 16 * 132; i += 256) ((float*)ctx_lds)[i] = 0.f;

    // Q fragments: 16 rows x 128 d
    short8 qa[4];
    const short* qb = qs + ((size_t)(b * QL + q0 + c)) * DM + h * DH + g * 8;
#pragma unroll
    for (int ks = 0; ks < 4; ++ks) qa[ks] = *(const short8*)(qb + ks * 32);

    const short* vb0 = vs + ((size_t)(b * VL)) * DM + h * DH + g * 8;

    // pass 1: partial row sums of sigmoid(score) over this wave's chunk
    float rsum[4] = {0.f, 0.f, 0.f, 0.f};
    for (int v0 = vbase; v0 < vbase + 512; v0 += 64) {
#pragma unroll
        for (int ni = 0; ni < 4; ++ni) {
            f32x4 s = {0.f, 0.f, 0.f, 0.f};
            const short* vb = vb0 + (size_t)(v0 + ni * 16 + c) * DM;
#pragma unroll
            for (int ks = 0; ks < 4; ++ks)
                s = __builtin_amdgcn_mfma_f32_16x16x32_bf16(qa[ks], *(const short8*)(vb + ks * 32), s, 0, 0, 0);
#pragma unroll
            for (int r = 0; r < 4; ++r)
                rsum[r] += 1.f / (1.f + __expf(-s[r] * sc));
        }
    }
    // in-wave reduce across the 16 c-lanes
#pragma unroll
    for (int off = 1; off < 16; off <<= 1) {
#pragma unroll
        for (int r = 0; r < 4; ++r) rsum[r] += __shfl_xor(rsum[r], off);
    }
    if (c == 0) {
#pragma unroll
        for (int r = 0; r < 4; ++r) rs[wave][g * 4 + r] = rsum[r];
    }
    __syncthreads();   // also orders ctx_lds zeroing before atomics
    float inv[4];
#pragma unroll
    for (int r = 0; r < 4; ++r)
        inv[r] = 1.f / (rs[0][g * 4 + r] + rs[1][g * 4 + r] + rs[2][g * 4 + r] + rs[3][g * 4 + r]);

    // pass 2: recompute S, write align, accumulate partial context
    f32x4 ctx[8] = {};
    float* ao = align_out + ((size_t)((h * NB + b) * QL + q0)) * VL;
    const short* vtb0 = vsT + ((size_t)((b * NH + h) * DH)) * VL + g * 8;
    for (int v0 = vbase; v0 < vbase + 512; v0 += 64) {
#pragma unroll
        for (int ni = 0; ni < 4; ++ni) {
            f32x4 s = {0.f, 0.f, 0.f, 0.f};
            const short* vb = vb0 + (size_t)(v0 + ni * 16 + c) * DM;
#pragma unroll
            for (int ks = 0; ks < 4; ++ks)
                s = __builtin_amdgcn_mfma_f32_16x16x32_bf16(qa[ks], *(const short8*)(vb + ks * 32), s, 0, 0, 0);
#pragma unroll
            for (int r = 0; r < 4; ++r) {
                float p = (1.f / (1.f + __expf(-s[r] * sc))) * inv[r];
                ao[(size_t)(4 * g + r) * VL + v0 + ni * 16 + c] = p;
                Pl[wave][4 * g + r][ni * 16 + c] = f2bf(p);
            }
        }
        short8 pa0 = *(const short8*)&Pl[wave][c][g * 8];
        short8 pa1 = *(const short8*)&Pl[wave][c][32 + g * 8];
#pragma unroll
        for (int df = 0; df < 8; ++df) {
            const short* tb = vtb0 + (size_t)(df * 16 + c) * VL + v0;
            ctx[df] = __builtin_amdgcn_mfma_f32_16x16x32_bf16(pa0, *(const short8*)(tb), ctx[df], 0, 0, 0);
            ctx[df] = __builtin_amdgcn_mfma_f32_16x16x32_bf16(pa1, *(const short8*)(tb + 32), ctx[df], 0, 0, 0);
        }
    }
    // cross-wave context reduction
#pragma unroll
    for (int df = 0; df < 8; ++df)
#pragma unroll
        for (int r = 0; r < 4; ++r)
            atomicAdd(&ctx_lds[4 * g + r][df * 16 + c], ctx[df][r]);
    __syncthreads();
    // write context (bf16) into combined[:, 0:1024]: 2048 elems, 8 per thread
    {
        const int row = (tid * 8) >> 7;
        const int col0 = (tid * 8) & 127;
        short8 o;
#pragma unroll
        for (int i = 0; i < 8; ++i) o[i] = f2bf(ctx_lds[row][col0 + i]);
        *(short8*)(comb + ((size_t)(b * QL + q0 + row)) * (2 * DM) + h * DH + col0) = o;
    }
}

// ---------- launch ----------
extern "C" void kernel_launch(void* const* d_in, const int* in_sizes, int n_in,
                              void* d_out, int out_size, void* d_ws, size_t ws_size,
                              hipStream_t stream) {
    (void)in_sizes; (void)n_in; (void)out_size; (void)ws_size;
    const float* Q    = (const float*)d_in[0];
    const float* V    = (const float*)d_in[1];
    const float* la   = (const float*)d_in[2];
    const float* cw   = (const float*)d_in[3];
    const float* cb   = (const float*)d_in[4];
    const float* Wq   = (const float*)d_in[5];
    const float* bq   = (const float*)d_in[6];
    const float* Wv   = (const float*)d_in[7];
    const float* bv   = (const float*)d_in[8];
    const float* Wu   = (const float*)d_in[9];
    const float* bu   = (const float*)d_in[10];
    const float* bias = (const float*)d_in[11];
    const float* fcw  = (const float*)d_in[12];
    const float* fcb  = (const float*)d_in[13];

    float* out = (float*)d_out;
    float* align_out = out + (size_t)NB * QL * DM;   // 4,194,304

    char* w = (char*)d_ws;
    short* Aq   = (short*)w; w += (size_t)4096 * KQ * 2;       // 8.9 MB
    short* Bq   = (short*)w; w += (size_t)1024 * KQ * 2;       // 2.2 MB
    short* Bvw  = (short*)w; w += (size_t)1024 * 1024 * 2;     // 2 MB
    short* Bfc  = (short*)w; w += (size_t)1024 * 2048 * 2;     // 4 MB
    short* qsb  = (short*)w; w += (size_t)4096 * 1024 * 2;     // 8 MB
    short* vsb  = (short*)w; w += (size_t)16384 * 1024 * 2;    // 32 MB
    short* vsT  = (short*)w; w += (size_t)16384 * 1024 * 2;    // 32 MB
    short* comb = (short*)w; w += (size_t)4096 * 2048 * 2;     // 16 MB
    float* cbias = (float*)w; w += 1024 * 4;

    cbias_k<<<4, 256, 0, stream>>>(bq, bu, bias, cbias);
    conv_prep_k<<<16, 256, 0, stream>>>(la, cw, cb, Aq);
    castq_k<<<2048, 256, 0, stream>>>(Q, Aq, comb);
    {
        int total = 1024 * KQ + 1024 * 1024 + 1024 * 2048;
        buildw_k<<<(total + 255) / 256, 256, 0, stream>>>(Wq, Wu, Wv, fcw, Bq, Bvw, Bfc);
    }
    // q_s = [Q|U] @ [Wq|Wu]^T + (bq+bu+bias)
    gemm_k<short, 1><<<dim3(32 * 8), 256, 0, stream>>>(Aq, Bq, cbias, qsb, nullptr, 4096, 1024, KQ, 1024);
    // v_s = V @ Wv^T + bv  (+ transposed copy per head)
    gemm_k<float, 0><<<dim3(128 * 8), 256, 0, stream>>>(V, Bvw, bv, vsb, vsT, 16384, 1024, 1024, 1024);
    // attention (writes align to d_out, context into combined[:, :1024])
    attn_k<<<2048, 256, 0, stream>>>(qsb, vsb, vsT, align_out, comb);
    // output = tanh(combined @ fc_w^T + fc_b)
    gemm_k<short, 2><<<dim3(32 * 8), 256, 0, stream>>>(comb, Bfc, fcb, out, nullptr, 4096, 1024, 2048, 1024);
}

// Round 3
// 451.323 us; speedup vs baseline: 1.5075x; 1.4196x over previous
//
#include <hip/hip_runtime.h>

// ---------- types ----------
typedef __attribute__((ext_vector_type(8))) short short8;
typedef __attribute__((ext_vector_type(4))) short short4v;
typedef __attribute__((ext_vector_type(4))) float f32x4;

static __device__ __forceinline__ short f2bf(float x) {
    unsigned u = __builtin_bit_cast(unsigned, x);
    unsigned r = (u + 0x7fffu + ((u >> 16) & 1u)) >> 16;
    return (short)r;
}

#define QL 512
#define VL 2048
#define DM 1024
#define NH 8
#define DH 128
#define NB 8
#define KQ 1088   // 1024 + 64 (U columns padded)

// ---------- tiny prep kernels ----------
__global__ void cbias_k(const float* __restrict__ bq, const float* __restrict__ bu,
                        const float* __restrict__ bias, float* __restrict__ cbias) {
    int i = blockIdx.x * 256 + threadIdx.x;
    if (i < DM) cbias[i] = bq[i] + bu[i] + bias[i];
}

// conv1d over last_align -> bf16 into Aq[:, 1024:1088] (cols 1034..1087 zero)
__global__ void conv_prep_k(const float* __restrict__ la, const float* __restrict__ cw,
                            const float* __restrict__ cb, short* __restrict__ Aq) {
    int m = blockIdx.x * 256 + threadIdx.x;      // 0..4095
    if (m >= NB * QL) return;
    int b = m >> 9, t = m & 511;
    const float* l = la + b * QL;
    float lm = (t > 0)      ? l[t - 1] : 0.f;
    float l0 = l[t];
    float lp = (t < QL - 1) ? l[t + 1] : 0.f;
    short* row = Aq + (size_t)m * KQ + 1024;
#pragma unroll
    for (int k = 0; k < 10; ++k)
        row[k] = f2bf(cb[k] + lm * cw[k * 3 + 0] + l0 * cw[k * 3 + 1] + lp * cw[k * 3 + 2]);
    for (int k = 10; k < 64; ++k) row[k] = 0;
}

// cast Q -> Aq[:, 0:1024] and combined[:, 1024:2048]
__global__ void castq_k(const float* __restrict__ Q, short* __restrict__ Aq,
                        short* __restrict__ comb) {
    int id = blockIdx.x * 256 + threadIdx.x;     // 0..524287
    int m = id >> 7, kc = (id & 127) * 8;
    const float* p = Q + (size_t)m * DM + kc;
    float4 f0 = *(const float4*)p;
    float4 f1 = *(const float4*)(p + 4);
    short8 v;
    v[0]=f2bf(f0.x); v[1]=f2bf(f0.y); v[2]=f2bf(f0.z); v[3]=f2bf(f0.w);
    v[4]=f2bf(f1.x); v[5]=f2bf(f1.y); v[6]=f2bf(f1.z); v[7]=f2bf(f1.w);
    *(short8*)(Aq + (size_t)m * KQ + kc) = v;
    *(short8*)(comb + (size_t)m * (2 * DM) + DM + kc) = v;
}

// cast weights: Bq = [Wq | Wu | 0], Bv = Wv, Bfc = fc_w  (all bf16, N x K row-major)
__global__ void buildw_k(const float* __restrict__ Wq, const float* __restrict__ Wu,
                         const float* __restrict__ Wv, const float* __restrict__ fcw,
                         short* __restrict__ Bq, short* __restrict__ Bv, short* __restrict__ Bfc) {
    int id = blockIdx.x * 256 + threadIdx.x;
    const int nq = DM * KQ;             // 1024*1088
    const int nv = DM * DM;             // 1024*1024
    const int nf = DM * 2 * DM;         // 1024*2048
    if (id < nq) {
        int n = id / KQ, k = id % KQ;
        float v = (k < 1024) ? Wq[(size_t)n * 1024 + k]
                             : ((k < 1034) ? Wu[n * 10 + (k - 1024)] : 0.f);
        Bq[id] = f2bf(v);
    } else if (id < nq + nv) {
        int j = id - nq;
        Bv[j] = f2bf(Wv[j]);
    } else if (id < nq + nv + nf) {
        int j = id - nq - nv;
        Bfc[j] = f2bf(fcw[j]);
    }
}

// ---------- generic MFMA GEMM: C[m][n] = sum_k A[m][k]*B[n][k] (+bias epilogues) ----------
// MODE 0: v_s  — bf16 out (out_ld) + transposed bf16 out vT[(b*8+h)*128+hd][v]
// MODE 1: q_s  — bf16 out
// MODE 2: fc   — f32 out = tanh(val + bias)
template <typename AT, int MODE>
__global__ __launch_bounds__(256) void gemm_k(
    const AT* __restrict__ A, const short* __restrict__ B,
    const float* __restrict__ bias, void* __restrict__ out0,
    short* __restrict__ outT, int M, int N, int K, int out_ld) {
    __shared__ short As[128][72];
    __shared__ short Bs[128][72];
    const int tid = threadIdx.x;
    const int lane = tid & 63, wave = tid >> 6;
    const int g = lane >> 4, c = lane & 15;
    const int nbm = M >> 7;
    const int bm = blockIdx.x % nbm, bn = blockIdx.x / nbm;
    const int wr = wave >> 1, wc = wave & 1;

    // staging pointers (4 chunks of 8 elems per thread per operand)
    const AT* aptr[4];
    const short* bptr[4];
    short* asl[4];
    short* bsl[4];
#pragma unroll
    for (int i = 0; i < 4; ++i) {
        int id = tid * 4 + i;           // 0..1023
        int row = id >> 3;              // 0..127
        int kc = (id & 7) * 8;          // 0..56
        aptr[i] = A + (size_t)(bm * 128 + row) * K + kc;
        bptr[i] = B + (size_t)(bn * 128 + row) * K + kc;
        asl[i] = &As[row][kc];
        bsl[i] = &Bs[row][kc];
    }

    f32x4 acc[4][4] = {};

    for (int k0 = 0; k0 < K; k0 += 64) {
        __syncthreads();
#pragma unroll
        for (int i = 0; i < 4; ++i) {
            short8 av;
            if constexpr (sizeof(AT) == 4) {
                const float* ap = (const float*)(aptr[i]) + k0;
                float4 f0 = *(const float4*)ap;
                float4 f1 = *(const float4*)(ap + 4);
                av[0]=f2bf(f0.x); av[1]=f2bf(f0.y); av[2]=f2bf(f0.z); av[3]=f2bf(f0.w);
                av[4]=f2bf(f1.x); av[5]=f2bf(f1.y); av[6]=f2bf(f1.z); av[7]=f2bf(f1.w);
            } else {
                av = *(const short8*)((const short*)(aptr[i]) + k0);
            }
            *(short8*)asl[i] = av;
            *(short8*)bsl[i] = *(const short8*)(bptr[i] + k0);
        }
        __syncthreads();
#pragma unroll
        for (int ks = 0; ks < 2; ++ks) {
            short8 af[4], bfr[4];
#pragma unroll
            for (int mi = 0; mi < 4; ++mi) af[mi] = *(short8*)&As[wr * 64 + mi * 16 + c][ks * 32 + g * 8];
#pragma unroll
            for (int ni = 0; ni < 4; ++ni) bfr[ni] = *(short8*)&Bs[wc * 64 + ni * 16 + c][ks * 32 + g * 8];
#pragma unroll
            for (int mi = 0; mi < 4; ++mi)
#pragma unroll
                for (int ni = 0; ni < 4; ++ni)
                    acc[mi][ni] = __builtin_amdgcn_mfma_f32_16x16x32_bf16(af[mi], bfr[ni], acc[mi][ni], 0, 0, 0);
        }
    }

    const int m0 = bm * 128 + wr * 64, n0 = bn * 128 + wc * 64;
#pragma unroll
    for (int ni = 0; ni < 4; ++ni) {
        int n = n0 + ni * 16 + c;
        float bn_ = bias[n];
#pragma unroll
        for (int mi = 0; mi < 4; ++mi) {
            int mb = m0 + mi * 16 + 4 * g;
            f32x4 v = acc[mi][ni];
            if constexpr (MODE == 2) {
                float* o = (float*)out0;
#pragma unroll
                for (int r = 0; r < 4; ++r)
                    o[(size_t)(mb + r) * out_ld + n] = tanhf(v[r] + bn_);
            } else {
                short* o = (short*)out0;
                short4v pk;
#pragma unroll
                for (int r = 0; r < 4; ++r) {
                    pk[r] = f2bf(v[r] + bn_);
                    o[(size_t)(mb + r) * out_ld + n] = pk[r];
                }
                if constexpr (MODE == 0) {
                    int h = n >> 7, hd = n & 127;
                    int bb = mb >> 11, vv = mb & 2047;
                    *(short4v*)(outT + ((size_t)((bb * NH + h) * DH + hd)) * VL + vv) = pk;
                }
            }
        }
    }
}

// ---------- score kernel ----------
// Per (b,h): S = q_s_head (512x128) @ v_s_head^T (128x2048), p = sigmoid(S/sqrt(128)).
// Writes UNNORMALIZED p (f32) into the align region of d_out; writes partial
// row sums (per 64-col strip) to rsum_part[(bh*512+q)*32 + bn*2+wc].
__global__ __launch_bounds__(256) void score_k(
    const short* __restrict__ qs, const short* __restrict__ vs,
    float* __restrict__ palign, float* __restrict__ rsum_part) {
    __shared__ short As[128][72];
    __shared__ short Bs[128][72];
    // decode with XCD grouping: phys%8 = bh&7
    const int blk = blockIdx.x;
    const int xr = blk & 7, t = blk >> 3;
    const int bn = t & 15;          // 16 col tiles of 128 v
    const int bm = (t >> 4) & 3;    // 4 row tiles of 128 q
    const int bh = ((t >> 6) << 3) | xr;
    const int h = bh & 7, b = bh >> 3;

    const int tid = threadIdx.x;
    const int lane = tid & 63, wave = tid >> 6;
    const int g = lane >> 4, c = lane & 15;
    const int wr = wave >> 1, wc = wave & 1;
    const float sc = 0.08838834764831845f;   // 1/sqrt(128)

    const short* Abase = qs + (size_t)(b * QL) * DM + h * DH;       // row stride DM
    const short* Bbase = vs + (size_t)(b * VL) * DM + h * DH;       // row stride DM

    const short* aptr[4];
    const short* bptr[4];
    short* asl[4];
    short* bsl[4];
#pragma unroll
    for (int i = 0; i < 4; ++i) {
        int id = tid * 4 + i;
        int row = id >> 3;
        int kc = (id & 7) * 8;
        aptr[i] = Abase + (size_t)(bm * 128 + row) * DM + kc;
        bptr[i] = Bbase + (size_t)(bn * 128 + row) * DM + kc;
        asl[i] = &As[row][kc];
        bsl[i] = &Bs[row][kc];
    }

    f32x4 acc[4][4] = {};
    for (int k0 = 0; k0 < DH; k0 += 64) {
        __syncthreads();
#pragma unroll
        for (int i = 0; i < 4; ++i) {
            *(short8*)asl[i] = *(const short8*)(aptr[i] + k0);
            *(short8*)bsl[i] = *(const short8*)(bptr[i] + k0);
        }
        __syncthreads();
#pragma unroll
        for (int ks = 0; ks < 2; ++ks) {
            short8 af[4], bfr[4];
#pragma unroll
            for (int mi = 0; mi < 4; ++mi) af[mi] = *(short8*)&As[wr * 64 + mi * 16 + c][ks * 32 + g * 8];
#pragma unroll
            for (int ni = 0; ni < 4; ++ni) bfr[ni] = *(short8*)&Bs[wc * 64 + ni * 16 + c][ks * 32 + g * 8];
#pragma unroll
            for (int mi = 0; mi < 4; ++mi)
#pragma unroll
                for (int ni = 0; ni < 4; ++ni)
                    acc[mi][ni] = __builtin_amdgcn_mfma_f32_16x16x32_bf16(af[mi], bfr[ni], acc[mi][ni], 0, 0, 0);
        }
    }

    // epilogue: sigmoid -> p f32 store + partial row sums
    float psum[4][4];
#pragma unroll
    for (int mi = 0; mi < 4; ++mi)
#pragma unroll
        for (int r = 0; r < 4; ++r) psum[mi][r] = 0.f;

    const int m0 = bm * 128 + wr * 64, n0 = bn * 128 + wc * 64;
    float* pbase = palign + (size_t)(bh * QL) * VL;
#pragma unroll
    for (int ni = 0; ni < 4; ++ni) {
        int n = n0 + ni * 16 + c;
#pragma unroll
        for (int mi = 0; mi < 4; ++mi) {
            int mb = m0 + mi * 16 + 4 * g;
            f32x4 v = acc[mi][ni];
#pragma unroll
            for (int r = 0; r < 4; ++r) {
                float p = 1.f / (1.f + __expf(-v[r] * sc));
                pbase[(size_t)(mb + r) * VL + n] = p;
                psum[mi][r] += p;
            }
        }
    }
    // reduce over the 16 c-lanes (offsets 1,2,4,8 stay within the 16-group)
#pragma unroll
    for (int off = 1; off < 16; off <<= 1)
#pragma unroll
        for (int mi = 0; mi < 4; ++mi)
#pragma unroll
            for (int r = 0; r < 4; ++r) psum[mi][r] += __shfl_xor(psum[mi][r], off);
    if (c == 0) {
#pragma unroll
        for (int mi = 0; mi < 4; ++mi)
#pragma unroll
            for (int r = 0; r < 4; ++r) {
                int q = m0 + mi * 16 + 4 * g + r;
                rsum_part[(size_t)(bh * QL + q) * 32 + bn * 2 + wc] = psum[mi][r];
            }
    }
}

// ---------- row-sum reduce: inv = 1/sum(32 partials) ----------
__global__ void rsred_k(const float* __restrict__ rsum_part, float* __restrict__ rsinv) {
    int id = blockIdx.x * 256 + threadIdx.x;   // 0..32767
    if (id >= NB * NH * QL) return;
    const float* p = rsum_part + (size_t)id * 32;
    float s = 0.f;
#pragma unroll
    for (int j = 0; j < 32; ++j) s += p[j];
    rsinv[id] = 1.f / s;
}

// ---------- PV kernel ----------
// Per (bh, 64-q tile): ctx = p @ vsT_head^T; stages p (f32->bf16) from the align
// buffer and writes back p*inv IN PLACE (exact element ownership per thread);
// epilogue: ctx*inv -> bf16 into comb[:, 0:1024].
__global__ __launch_bounds__(512) void pv_k(
    float* __restrict__ palign, const short* __restrict__ vsT,
    const float* __restrict__ rsinv, short* __restrict__ comb) {
    __shared__ short As[64][72];
    __shared__ short Bs[128][72];
    const int blk = blockIdx.x;                 // 512
    const int xr = blk & 7, t = blk >> 3;
    const int bm = t & 7;                       // 8 q-tiles of 64
    const int bh = ((t >> 3) << 3) | xr;
    const int h = bh & 7, b = bh >> 3;

    const int tid = threadIdx.x;
    const int lane = tid & 63, wave = tid >> 6;
    const int g = lane >> 4, c = lane & 15;
    const int wr = wave >> 2, wc = wave & 3;    // 2 x 4 wave grid

    // A staging: 1 chunk of 8 per thread (64 rows x 64 k f32)
    const int arow = tid >> 3, akc = (tid & 7) * 8;
    float* aptr = palign + ((size_t)(bh * QL + bm * 64 + arow)) * VL + akc;
    const float inv_a = rsinv[bh * QL + bm * 64 + arow];
    short* asl = &As[arow][akc];
    // B staging: 2 chunks (128 rows x 64 k bf16)
    const short* bptr[2];
    short* bsl[2];
#pragma unroll
    for (int i = 0; i < 2; ++i) {
        int id = tid * 2 + i;
        int row = id >> 3, kc = (id & 7) * 8;
        bptr[i] = vsT + ((size_t)(bh * DH + row)) * VL + kc;
        bsl[i] = &Bs[row][kc];
    }

    f32x4 acc[2][2] = {};
    for (int k0 = 0; k0 < VL; k0 += 64) {
        __syncthreads();
        {
            float4 f0 = *(const float4*)(aptr + k0);
            float4 f1 = *(const float4*)(aptr + k0 + 4);
            short8 av;
            av[0]=f2bf(f0.x); av[1]=f2bf(f0.y); av[2]=f2bf(f0.z); av[3]=f2bf(f0.w);
            av[4]=f2bf(f1.x); av[5]=f2bf(f1.y); av[6]=f2bf(f1.z); av[7]=f2bf(f1.w);
            *(short8*)asl = av;
            // in-place normalize (same elements this thread just read)
            f0.x*=inv_a; f0.y*=inv_a; f0.z*=inv_a; f0.w*=inv_a;
            f1.x*=inv_a; f1.y*=inv_a; f1.z*=inv_a; f1.w*=inv_a;
            *(float4*)(aptr + k0) = f0;
            *(float4*)(aptr + k0 + 4) = f1;
#pragma unroll
            for (int i = 0; i < 2; ++i) *(short8*)bsl[i] = *(const short8*)(bptr[i] + k0);
        }
        __syncthreads();
#pragma unroll
        for (int ks = 0; ks < 2; ++ks) {
            short8 af[2], bfr[2];
#pragma unroll
            for (int mi = 0; mi < 2; ++mi) af[mi] = *(short8*)&As[wr * 32 + mi * 16 + c][ks * 32 + g * 8];
#pragma unroll
            for (int ni = 0; ni < 2; ++ni) bfr[ni] = *(short8*)&Bs[wc * 32 + ni * 16 + c][ks * 32 + g * 8];
#pragma unroll
            for (int mi = 0; mi < 2; ++mi)
#pragma unroll
                for (int ni = 0; ni < 2; ++ni)
                    acc[mi][ni] = __builtin_amdgcn_mfma_f32_16x16x32_bf16(af[mi], bfr[ni], acc[mi][ni], 0, 0, 0);
        }
    }

    // epilogue: ctx * inv -> comb
#pragma unroll
    for (int mi = 0; mi < 2; ++mi) {
        int mloc = wr * 32 + mi * 16 + 4 * g;
#pragma unroll
        for (int r = 0; r < 4; ++r) {
            int q = bm * 64 + mloc + r;
            float inv = rsinv[bh * QL + q];
#pragma unroll
            for (int ni = 0; ni < 2; ++ni) {
                int d = wc * 32 + ni * 16 + c;
                comb[((size_t)(b * QL + q)) * (2 * DM) + h * DH + d] = f2bf(acc[mi][ni][r] * inv);
            }
        }
    }
}

// ---------- launch ----------
extern "C" void kernel_launch(void* const* d_in, const int* in_sizes, int n_in,
                              void* d_out, int out_size, void* d_ws, size_t ws_size,
                              hipStream_t stream) {
    (void)in_sizes; (void)n_in; (void)out_size; (void)ws_size;
    const float* Q    = (const float*)d_in[0];
    const float* V    = (const float*)d_in[1];
    const float* la   = (const float*)d_in[2];
    const float* cw   = (const float*)d_in[3];
    const float* cb   = (const float*)d_in[4];
    const float* Wq   = (const float*)d_in[5];
    const float* bq   = (const float*)d_in[6];
    const float* Wv   = (const float*)d_in[7];
    const float* bv   = (const float*)d_in[8];
    const float* Wu   = (const float*)d_in[9];
    const float* bu   = (const float*)d_in[10];
    const float* bias = (const float*)d_in[11];
    const float* fcw  = (const float*)d_in[12];
    const float* fcb  = (const float*)d_in[13];

    float* out = (float*)d_out;
    float* align_out = out + (size_t)NB * QL * DM;   // 4,194,304 floats in, then align

    char* w = (char*)d_ws;
    short* Aq   = (short*)w; w += (size_t)4096 * KQ * 2;       // 8.9 MB
    short* Bq   = (short*)w; w += (size_t)1024 * KQ * 2;       // 2.2 MB
    short* Bvw  = (short*)w; w += (size_t)1024 * 1024 * 2;     // 2 MB
    short* Bfc  = (short*)w; w += (size_t)1024 * 2048 * 2;     // 4 MB
    short* qsb  = (short*)w; w += (size_t)4096 * 1024 * 2;     // 8 MB
    short* vsb  = (short*)w; w += (size_t)16384 * 1024 * 2;    // 32 MB
    short* vsT  = (short*)w; w += (size_t)16384 * 1024 * 2;    // 32 MB
    short* comb = (short*)w; w += (size_t)4096 * 2048 * 2;     // 16 MB
    float* cbias = (float*)w; w += 1024 * 4;
    float* rsum_part = (float*)w; w += (size_t)32768 * 32 * 4; // 4 MB
    float* rsinv = (float*)w; w += 32768 * 4;                  // 128 KB

    cbias_k<<<4, 256, 0, stream>>>(bq, bu, bias, cbias);
    conv_prep_k<<<16, 256, 0, stream>>>(la, cw, cb, Aq);
    castq_k<<<2048, 256, 0, stream>>>(Q, Aq, comb);
    {
        int total = 1024 * KQ + 1024 * 1024 + 1024 * 2048;
        buildw_k<<<(total + 255) / 256, 256, 0, stream>>>(Wq, Wu, Wv, fcw, Bq, Bvw, Bfc);
    }
    // q_s = [Q|U] @ [Wq|Wu]^T + (bq+bu+bias)
    gemm_k<short, 1><<<dim3(32 * 8), 256, 0, stream>>>(Aq, Bq, cbias, qsb, nullptr, 4096, 1024, KQ, 1024);
    // v_s = V @ Wv^T + bv  (+ transposed copy per head)
    gemm_k<float, 0><<<dim3(128 * 8), 256, 0, stream>>>(V, Bvw, bv, vsb, vsT, 16384, 1024, 1024, 1024);
    // attention, split:
    score_k<<<4096, 256, 0, stream>>>(qsb, vsb, align_out, rsum_part);
    rsred_k<<<128, 256, 0, stream>>>(rsum_part, rsinv);
    pv_k<<<512, 512, 0, stream>>>(align_out, vsT, rsinv, comb);
    // output = tanh(combined @ fc_w^T + fc_b)
    gemm_k<short, 2><<<dim3(32 * 8), 256, 0, stream>>>(comb, Bfc, fcb, out, nullptr, 4096, 1024, 2048, 1024);
}

// Round 4
// 408.596 us; speedup vs baseline: 1.6652x; 1.1046x over previous
//
#include <hip/hip_runtime.h>

// ---------- types ----------
typedef __attribute__((ext_vector_type(8))) short short8;
typedef __attribute__((ext_vector_type(4))) short short4v;
typedef __attribute__((ext_vector_type(4))) float f32x4;

static __device__ __forceinline__ short f2bf(float x) {
    unsigned u = __builtin_bit_cast(unsigned, x);
    unsigned r = (u + 0x7fffu + ((u >> 16) & 1u)) >> 16;
    return (short)r;
}

// async global->LDS, 16B per lane: lds dest = uniform base + lane*16
static __device__ __forceinline__ void gld16(const short* g, short* l) {
    __builtin_amdgcn_global_load_lds((const __attribute__((address_space(1))) void*)g,
                                     (__attribute__((address_space(3))) void*)l, 16, 0, 0);
}

#define QL 512
#define VL 2048
#define DM 1024
#define NH 8
#define DH 128
#define NB 8
#define KQ 1088   // 1024 + 64 (U columns padded)

// ---------- tiny prep kernels ----------
__global__ void cbias_k(const float* __restrict__ bq, const float* __restrict__ bu,
                        const float* __restrict__ bias, float* __restrict__ cbias) {
    int i = blockIdx.x * 256 + threadIdx.x;
    if (i < DM) cbias[i] = bq[i] + bu[i] + bias[i];
}

// conv1d over last_align -> bf16 into Aq[:, 1024:1088] (cols 1034..1087 zero)
__global__ void conv_prep_k(const float* __restrict__ la, const float* __restrict__ cw,
                            const float* __restrict__ cb, short* __restrict__ Aq) {
    int m = blockIdx.x * 256 + threadIdx.x;      // 0..4095
    if (m >= NB * QL) return;
    int b = m >> 9, t = m & 511;
    const float* l = la + b * QL;
    float lm = (t > 0)      ? l[t - 1] : 0.f;
    float l0 = l[t];
    float lp = (t < QL - 1) ? l[t + 1] : 0.f;
    short* row = Aq + (size_t)m * KQ + 1024;
#pragma unroll
    for (int k = 0; k < 10; ++k)
        row[k] = f2bf(cb[k] + lm * cw[k * 3 + 0] + l0 * cw[k * 3 + 1] + lp * cw[k * 3 + 2]);
    for (int k = 10; k < 64; ++k) row[k] = 0;
}

// cast Q -> Aq[:, 0:1024] and combined[:, 1024:2048]
__global__ void castq_k(const float* __restrict__ Q, short* __restrict__ Aq,
                        short* __restrict__ comb) {
    int id = blockIdx.x * 256 + threadIdx.x;     // 0..524287
    int m = id >> 7, kc = (id & 127) * 8;
    const float* p = Q + (size_t)m * DM + kc;
    float4 f0 = *(const float4*)p;
    float4 f1 = *(const float4*)(p + 4);
    short8 v;
    v[0]=f2bf(f0.x); v[1]=f2bf(f0.y); v[2]=f2bf(f0.z); v[3]=f2bf(f0.w);
    v[4]=f2bf(f1.x); v[5]=f2bf(f1.y); v[6]=f2bf(f1.z); v[7]=f2bf(f1.w);
    *(short8*)(Aq + (size_t)m * KQ + kc) = v;
    *(short8*)(comb + (size_t)m * (2 * DM) + DM + kc) = v;
}

// cast V -> bf16
__global__ void castv_k(const float* __restrict__ V, short* __restrict__ Vb) {
    int id = blockIdx.x * 256 + threadIdx.x;     // 0..2097151, 8 elems each
    const float* p = V + (size_t)id * 8;
    float4 f0 = *(const float4*)p;
    float4 f1 = *(const float4*)(p + 4);
    short8 v;
    v[0]=f2bf(f0.x); v[1]=f2bf(f0.y); v[2]=f2bf(f0.z); v[3]=f2bf(f0.w);
    v[4]=f2bf(f1.x); v[5]=f2bf(f1.y); v[6]=f2bf(f1.z); v[7]=f2bf(f1.w);
    *(short8*)(Vb + (size_t)id * 8) = v;
}

// cast weights: Bq = [Wq | Wu | 0], Bv = Wv, Bfc = fc_w  (all bf16, N x K row-major)
__global__ void buildw_k(const float* __restrict__ Wq, const float* __restrict__ Wu,
                         const float* __restrict__ Wv, const float* __restrict__ fcw,
                         short* __restrict__ Bq, short* __restrict__ Bv, short* __restrict__ Bfc) {
    int id = blockIdx.x * 256 + threadIdx.x;
    const int nq = DM * KQ;             // 1024*1088
    const int nv = DM * DM;             // 1024*1024
    const int nf = DM * 2 * DM;         // 1024*2048
    if (id < nq) {
        int n = id / KQ, k = id % KQ;
        float v = (k < 1024) ? Wq[(size_t)n * 1024 + k]
                             : ((k < 1034) ? Wu[n * 10 + (k - 1024)] : 0.f);
        Bq[id] = f2bf(v);
    } else if (id < nq + nv) {
        int j = id - nq;
        Bv[j] = f2bf(Wv[j]);
    } else if (id < nq + nv + nf) {
        int j = id - nq - nv;
        Bfc[j] = f2bf(fcw[j]);
    }
}

// ---------- m97-style MFMA GEMM: C[m][n] = sum_k A[m][k]*B[n][k] ----------
// linear LDS + global_load_lds(16B) staging, XCD-striped block order (nbn==8, nbm%8==0)
// MODE 0: v_s  — bf16 out + transposed bf16 out vT[(b*8+h)*128+hd][v]
// MODE 1: q_s  — bf16 out
// MODE 2: fc   — f32 out = tanh(val + bias)
template <int MODE>
__global__ __launch_bounds__(256) void gemm2_k(
    const short* __restrict__ A, const short* __restrict__ B,
    const float* __restrict__ bias, void* __restrict__ out0,
    short* __restrict__ outT, int M, int N, int K, int out_ld) {
    __shared__ short As[128 * 64];
    __shared__ short Bs[128 * 64];
    const int tid = threadIdx.x;
    const int lane = tid & 63, wave = tid >> 6;
    const int g = lane >> 4, c = lane & 15;
    const int nbm = M >> 7;
    // XCD stripes: blocks with same blockIdx%8 share an XCD; bn fast within stripe
    const int x = blockIdx.x & 7, j = blockIdx.x >> 3;
    const int bm = x * (nbm >> 3) + (j >> 3);
    const int bn = j & 7;
    const int wr = wave >> 1, wc = wave & 1;

    // staging: 4 chunks per wave per operand; chunk = 8 rows x 64 cols (1KB)
    const int srow = lane >> 3, scol = (lane & 7) * 8;
    const short* ag = A + (size_t)(bm * 128 + wave * 32 + srow) * K + scol;
    const short* bg = B + (size_t)(bn * 128 + wave * 32 + srow) * K + scol;

    f32x4 acc[4][4] = {};
    for (int k0 = 0; k0 < K; k0 += 64) {
#pragma unroll
        for (int ch = 0; ch < 4; ++ch) {
            gld16(ag + (size_t)(ch * 8) * K + k0, As + (wave * 32 + ch * 8) * 64);
            gld16(bg + (size_t)(ch * 8) * K + k0, Bs + (wave * 32 + ch * 8) * 64);
        }
        __syncthreads();
#pragma unroll
        for (int ks = 0; ks < 2; ++ks) {
            short8 af[4], bfr[4];
#pragma unroll
            for (int mi = 0; mi < 4; ++mi) af[mi] = *(const short8*)(As + (wr * 64 + mi * 16 + c) * 64 + ks * 32 + g * 8);
#pragma unroll
            for (int ni = 0; ni < 4; ++ni) bfr[ni] = *(const short8*)(Bs + (wc * 64 + ni * 16 + c) * 64 + ks * 32 + g * 8);
#pragma unroll
            for (int mi = 0; mi < 4; ++mi)
#pragma unroll
                for (int ni = 0; ni < 4; ++ni)
                    acc[mi][ni] = __builtin_amdgcn_mfma_f32_16x16x32_bf16(af[mi], bfr[ni], acc[mi][ni], 0, 0, 0);
        }
        __syncthreads();
    }

    const int m0 = bm * 128 + wr * 64, n0 = bn * 128 + wc * 64;
#pragma unroll
    for (int ni = 0; ni < 4; ++ni) {
        int n = n0 + ni * 16 + c;
        float bn_ = bias[n];
#pragma unroll
        for (int mi = 0; mi < 4; ++mi) {
            int mb = m0 + mi * 16 + 4 * g;
            f32x4 v = acc[mi][ni];
            if constexpr (MODE == 2) {
                float* o = (float*)out0;
#pragma unroll
                for (int r = 0; r < 4; ++r)
                    o[(size_t)(mb + r) * out_ld + n] = tanhf(v[r] + bn_);
            } else {
                short* o = (short*)out0;
                short4v pk;
#pragma unroll
                for (int r = 0; r < 4; ++r) {
                    pk[r] = f2bf(v[r] + bn_);
                    o[(size_t)(mb + r) * out_ld + n] = pk[r];
                }
                if constexpr (MODE == 0) {
                    int h = n >> 7, hd = n & 127;
                    int bb = mb >> 11, vv = mb & 2047;
                    *(short4v*)(outT + ((size_t)((bb * NH + h) * DH + hd)) * VL + vv) = pk;
                }
            }
        }
    }
}

// ---------- score kernel ----------
// Per (b,h): S = q_s_head (512x128) @ v_s_head^T (128x2048), p = sigmoid(S/sqrt(128)).
// Writes UNNORMALIZED p (f32) into the align region of d_out; partial row sums
// (per 64-col strip) to rsum_part[(bh*512+q)*32 + bn*2+wc].
__global__ __launch_bounds__(256) void score_k(
    const short* __restrict__ qs, const short* __restrict__ vs,
    float* __restrict__ palign, float* __restrict__ rsum_part) {
    __shared__ short As[128 * 64];
    __shared__ short Bs[128 * 64];
    // decode with XCD grouping: phys%8 = bh&7
    const int blk = blockIdx.x;
    const int xr = blk & 7, t = blk >> 3;
    const int bn = t & 15;          // 16 col tiles of 128 v
    const int bm = (t >> 4) & 3;    // 4 row tiles of 128 q
    const int bh = ((t >> 6) << 3) | xr;
    const int h = bh & 7, b = bh >> 3;

    const int tid = threadIdx.x;
    const int lane = tid & 63, wave = tid >> 6;
    const int g = lane >> 4, c = lane & 15;
    const int wr = wave >> 1, wc = wave & 1;
    const float sc = 0.08838834764831845f;   // 1/sqrt(128)

    const int srow = lane >> 3, scol = (lane & 7) * 8;
    const short* ag = qs + (size_t)(b * QL + bm * 128 + wave * 32 + srow) * DM + h * DH + scol;
    const short* bg = vs + (size_t)(b * VL + bn * 128 + wave * 32 + srow) * DM + h * DH + scol;

    f32x4 acc[4][4] = {};
    for (int k0 = 0; k0 < DH; k0 += 64) {
#pragma unroll
        for (int ch = 0; ch < 4; ++ch) {
            gld16(ag + (size_t)(ch * 8) * DM + k0, As + (wave * 32 + ch * 8) * 64);
            gld16(bg + (size_t)(ch * 8) * DM + k0, Bs + (wave * 32 + ch * 8) * 64);
        }
        __syncthreads();
#pragma unroll
        for (int ks = 0; ks < 2; ++ks) {
            short8 af[4], bfr[4];
#pragma unroll
            for (int mi = 0; mi < 4; ++mi) af[mi] = *(const short8*)(As + (wr * 64 + mi * 16 + c) * 64 + ks * 32 + g * 8);
#pragma unroll
            for (int ni = 0; ni < 4; ++ni) bfr[ni] = *(const short8*)(Bs + (wc * 64 + ni * 16 + c) * 64 + ks * 32 + g * 8);
#pragma unroll
            for (int mi = 0; mi < 4; ++mi)
#pragma unroll
                for (int ni = 0; ni < 4; ++ni)
                    acc[mi][ni] = __builtin_amdgcn_mfma_f32_16x16x32_bf16(af[mi], bfr[ni], acc[mi][ni], 0, 0, 0);
        }
        __syncthreads();
    }

    // epilogue: sigmoid -> p f32 store + partial row sums
    float psum[4][4];
#pragma unroll
    for (int mi = 0; mi < 4; ++mi)
#pragma unroll
        for (int r = 0; r < 4; ++r) psum[mi][r] = 0.f;

    const int m0 = bm * 128 + wr * 64, n0 = bn * 128 + wc * 64;
    float* pbase = palign + (size_t)(bh * QL) * VL;
#pragma unroll
    for (int ni = 0; ni < 4; ++ni) {
        int n = n0 + ni * 16 + c;
#pragma unroll
        for (int mi = 0; mi < 4; ++mi) {
            int mb = m0 + mi * 16 + 4 * g;
            f32x4 v = acc[mi][ni];
#pragma unroll
            for (int r = 0; r < 4; ++r) {
                float p = 1.f / (1.f + __expf(-v[r] * sc));
                pbase[(size_t)(mb + r) * VL + n] = p;
                psum[mi][r] += p;
            }
        }
    }
#pragma unroll
    for (int off = 1; off < 16; off <<= 1)
#pragma unroll
        for (int mi = 0; mi < 4; ++mi)
#pragma unroll
            for (int r = 0; r < 4; ++r) psum[mi][r] += __shfl_xor(psum[mi][r], off);
    if (c == 0) {
#pragma unroll
        for (int mi = 0; mi < 4; ++mi)
#pragma unroll
            for (int r = 0; r < 4; ++r) {
                int q = m0 + mi * 16 + 4 * g + r;
                rsum_part[(size_t)(bh * QL + q) * 32 + bn * 2 + wc] = psum[mi][r];
            }
    }
}

// ---------- PV kernel ----------
// Per (bh, 64-q tile): ctx = p @ vsT_head^T; fused rsum reduction; stages p
// (f32->bf16), writes back p*inv IN PLACE; epilogue ctx*inv -> comb ctx half.
__global__ __launch_bounds__(512) void pv_k(
    float* __restrict__ palign, const short* __restrict__ vsT,
    const float* __restrict__ rsum_part, short* __restrict__ comb) {
    __shared__ short As[64][72];
    __shared__ short Bs[128 * 64];
    __shared__ float rsl[64];
    const int blk = blockIdx.x;                 // 512
    const int xr = blk & 7, t = blk >> 3;
    const int bm = t & 7;                       // 8 q-tiles of 64
    const int bh = ((t >> 3) << 3) | xr;
    const int h = bh & 7, b = bh >> 3;

    const int tid = threadIdx.x;
    const int lane = tid & 63, wave = tid >> 6;
    const int g = lane >> 4, c = lane & 15;
    const int wr = wave >> 2, wc = wave & 3;    // 2 x 4 wave grid
    const int q0 = bm * 64;

    // fused row-sum reduce: inv = 1/sum(32 partials)
    if (tid < 64) {
        const float* p = rsum_part + (size_t)(bh * QL + q0 + tid) * 32;
        float s = 0.f;
#pragma unroll
        for (int jj = 0; jj < 32; ++jj) s += p[jj];
        rsl[tid] = 1.f / s;
    }
    __syncthreads();

    // A staging: 1 chunk of 8 f32 per thread (64 rows x 64 k)
    const int arow = tid >> 3, akc = (tid & 7) * 8;
    float* aptr = palign + ((size_t)(bh * QL + q0 + arow)) * VL + akc;
    const float inv_a = rsl[arow];
    short* asl = &As[arow][akc];
    // B staging: global_load_lds, 2 chunks per wave (8 waves, 128 rows x 64 k)
    const int srow = lane >> 3, scol = (lane & 7) * 8;
    const short* bg = vsT + ((size_t)(bh * DH + wave * 16 + srow)) * VL + scol;

    f32x4 acc[2][2] = {};
    for (int k0 = 0; k0 < VL; k0 += 64) {
        gld16(bg + k0, Bs + (wave * 16) * 64);
        gld16(bg + (size_t)8 * VL + k0, Bs + (wave * 16 + 8) * 64);
        {
            float4 f0 = *(const float4*)(aptr + k0);
            float4 f1 = *(const float4*)(aptr + k0 + 4);
            short8 av;
            av[0]=f2bf(f0.x); av[1]=f2bf(f0.y); av[2]=f2bf(f0.z); av[3]=f2bf(f0.w);
            av[4]=f2bf(f1.x); av[5]=f2bf(f1.y); av[6]=f2bf(f1.z); av[7]=f2bf(f1.w);
            *(short8*)asl = av;
            // in-place normalize (exact element ownership)
            f0.x*=inv_a; f0.y*=inv_a; f0.z*=inv_a; f0.w*=inv_a;
            f1.x*=inv_a; f1.y*=inv_a; f1.z*=inv_a; f1.w*=inv_a;
            *(float4*)(aptr + k0) = f0;
            *(float4*)(aptr + k0 + 4) = f1;
        }
        __syncthreads();
#pragma unroll
        for (int ks = 0; ks < 2; ++ks) {
            short8 af[2], bfr[2];
#pragma unroll
            for (int mi = 0; mi < 2; ++mi) af[mi] = *(short8*)&As[wr * 32 + mi * 16 + c][ks * 32 + g * 8];
#pragma unroll
            for (int ni = 0; ni < 2; ++ni) bfr[ni] = *(const short8*)(Bs + (wc * 32 + ni * 16 + c) * 64 + ks * 32 + g * 8);
#pragma unroll
            for (int mi = 0; mi < 2; ++mi)
#pragma unroll
                for (int ni = 0; ni < 2; ++ni)
                    acc[mi][ni] = __builtin_amdgcn_mfma_f32_16x16x32_bf16(af[mi], bfr[ni], acc[mi][ni], 0, 0, 0);
        }
        __syncthreads();
    }

    // epilogue: ctx * inv -> comb
#pragma unroll
    for (int mi = 0; mi < 2; ++mi) {
        int mloc = wr * 32 + mi * 16 + 4 * g;
#pragma unroll
        for (int r = 0; r < 4; ++r) {
            int q = q0 + mloc + r;
            float inv = rsl[mloc + r];
#pragma unroll
            for (int ni = 0; ni < 2; ++ni) {
                int d = wc * 32 + ni * 16 + c;
                comb[((size_t)(b * QL + q)) * (2 * DM) + h * DH + d] = f2bf(acc[mi][ni][r] * inv);
            }
        }
    }
}

// ---------- launch ----------
extern "C" void kernel_launch(void* const* d_in, const int* in_sizes, int n_in,
                              void* d_out, int out_size, void* d_ws, size_t ws_size,
                              hipStream_t stream) {
    (void)in_sizes; (void)n_in; (void)out_size; (void)ws_size;
    const float* Q    = (const float*)d_in[0];
    const float* V    = (const float*)d_in[1];
    const float* la   = (const float*)d_in[2];
    const float* cw   = (const float*)d_in[3];
    const float* cb   = (const float*)d_in[4];
    const float* Wq   = (const float*)d_in[5];
    const float* bq   = (const float*)d_in[6];
    const float* Wv   = (const float*)d_in[7];
    const float* bv   = (const float*)d_in[8];
    const float* Wu   = (const float*)d_in[9];
    const float* bu   = (const float*)d_in[10];
    const float* bias = (const float*)d_in[11];
    const float* fcw  = (const float*)d_in[12];
    const float* fcb  = (const float*)d_in[13];

    float* out = (float*)d_out;
    float* align_out = out + (size_t)NB * QL * DM;

    // ws layout with lifetime overlap: R0 (32MB) holds Vb first, then Aq+comb+cbias
    char* w = (char*)d_ws;
    char* R0 = w;                        w += (size_t)33554432;  // 32 MB
    short* Vb    = (short*)R0;                                   // 16384x1024 bf16 (dead after v_s)
    short* Aq    = (short*)R0;                                   // 4096x1088 bf16 = 8,912,896 B
    short* comb  = (short*)(R0 + 8912896);                       // 4096x2048 bf16 = 16,777,216 B
    float* cbias = (float*)(R0 + 8912896 + 16777216);            // 4 KB
    short* Bq   = (short*)w; w += (size_t)1024 * KQ * 2;         // 2.2 MB
    short* Bvw  = (short*)w; w += (size_t)1024 * 1024 * 2;       // 2 MB
    short* Bfc  = (short*)w; w += (size_t)1024 * 2048 * 2;       // 4 MB
    short* vsb  = (short*)w; w += (size_t)16384 * 1024 * 2;      // 32 MB
    short* vsT  = (short*)w; w += (size_t)16384 * 1024 * 2;      // 32 MB
    short* qsb  = (short*)w; w += (size_t)4096 * 1024 * 2;       // 8 MB
    float* rsum_part = (float*)w; w += (size_t)32768 * 32 * 4;   // 4 MB

    // phase 1: V path (Vb alive)
    castv_k<<<8192, 256, 0, stream>>>(V, Vb);
    {
        int total = 1024 * KQ + 1024 * 1024 + 1024 * 2048;
        buildw_k<<<(total + 255) / 256, 256, 0, stream>>>(Wq, Wu, Wv, fcw, Bq, Bvw, Bfc);
    }
    gemm2_k<0><<<1024, 256, 0, stream>>>(Vb, Bvw, bv, vsb, vsT, 16384, 1024, 1024, 1024);
    // phase 2: Q path (Aq/comb overwrite Vb region)
    cbias_k<<<4, 256, 0, stream>>>(bq, bu, bias, cbias);
    conv_prep_k<<<16, 256, 0, stream>>>(la, cw, cb, Aq);
    castq_k<<<2048, 256, 0, stream>>>(Q, Aq, comb);
    gemm2_k<1><<<256, 256, 0, stream>>>(Aq, Bq, cbias, qsb, nullptr, 4096, 1024, KQ, 1024);
    // attention
    score_k<<<4096, 256, 0, stream>>>(qsb, vsb, align_out, rsum_part);
    pv_k<<<512, 512, 0, stream>>>(align_out, vsT, rsum_part, comb);
    // output = tanh(combined @ fc_w^T + fc_b)
    gemm2_k<2><<<256, 256, 0, stream>>>(comb, Bfc, fcb, out, nullptr, 4096, 1024, 2048, 1024);
}

// Round 5
// 355.708 us; speedup vs baseline: 1.9128x; 1.1487x over previous
//
#include <hip/hip_runtime.h>

// ---------- types ----------
typedef __attribute__((ext_vector_type(8))) short short8;
typedef __attribute__((ext_vector_type(4))) short short4v;
typedef __attribute__((ext_vector_type(4))) float f32x4;

static __device__ __forceinline__ short f2bf(float x) {
    unsigned u = __builtin_bit_cast(unsigned, x);
    unsigned r = (u + 0x7fffu + ((u >> 16) & 1u)) >> 16;
    return (short)r;
}

// async global->LDS, 16B per lane: lds dest = uniform base + lane*16
static __device__ __forceinline__ void gld16(const short* g, short* l) {
    __builtin_amdgcn_global_load_lds((const __attribute__((address_space(1))) void*)g,
                                     (__attribute__((address_space(3))) void*)l, 16, 0, 0);
}

#define QL 512
#define VL 2048
#define DM 1024
#define NH 8
#define DH 128
#define NB 8
#define KQ 1088   // 1024 + 64 (U columns padded)

// ---------- tiny prep kernels ----------
__global__ void cbias_k(const float* __restrict__ bq, const float* __restrict__ bu,
                        const float* __restrict__ bias, float* __restrict__ cbias) {
    int i = blockIdx.x * 256 + threadIdx.x;
    if (i < DM) cbias[i] = bq[i] + bu[i] + bias[i];
}

// conv1d over last_align -> bf16 into Aq[:, 1024:1088] (cols 1034..1087 zero)
__global__ void conv_prep_k(const float* __restrict__ la, const float* __restrict__ cw,
                            const float* __restrict__ cb, short* __restrict__ Aq) {
    int m = blockIdx.x * 256 + threadIdx.x;      // 0..4095
    if (m >= NB * QL) return;
    int b = m >> 9, t = m & 511;
    const float* l = la + b * QL;
    float lm = (t > 0)      ? l[t - 1] : 0.f;
    float l0 = l[t];
    float lp = (t < QL - 1) ? l[t + 1] : 0.f;
    short* row = Aq + (size_t)m * KQ + 1024;
#pragma unroll
    for (int k = 0; k < 10; ++k)
        row[k] = f2bf(cb[k] + lm * cw[k * 3 + 0] + l0 * cw[k * 3 + 1] + lp * cw[k * 3 + 2]);
    for (int k = 10; k < 64; ++k) row[k] = 0;
}

// cast Q -> Aq[:, 0:1024] and combined[:, 1024:2048]
__global__ void castq_k(const float* __restrict__ Q, short* __restrict__ Aq,
                        short* __restrict__ comb) {
    int id = blockIdx.x * 256 + threadIdx.x;     // 0..524287
    int m = id >> 7, kc = (id & 127) * 8;
    const float* p = Q + (size_t)m * DM + kc;
    float4 f0 = *(const float4*)p;
    float4 f1 = *(const float4*)(p + 4);
    short8 v;
    v[0]=f2bf(f0.x); v[1]=f2bf(f0.y); v[2]=f2bf(f0.z); v[3]=f2bf(f0.w);
    v[4]=f2bf(f1.x); v[5]=f2bf(f1.y); v[6]=f2bf(f1.z); v[7]=f2bf(f1.w);
    *(short8*)(Aq + (size_t)m * KQ + kc) = v;
    *(short8*)(comb + (size_t)m * (2 * DM) + DM + kc) = v;
}

// cast V -> bf16
__global__ void castv_k(const float* __restrict__ V, short* __restrict__ Vb) {
    int id = blockIdx.x * 256 + threadIdx.x;     // 0..2097151, 8 elems each
    const float* p = V + (size_t)id * 8;
    float4 f0 = *(const float4*)p;
    float4 f1 = *(const float4*)(p + 4);
    short8 v;
    v[0]=f2bf(f0.x); v[1]=f2bf(f0.y); v[2]=f2bf(f0.z); v[3]=f2bf(f0.w);
    v[4]=f2bf(f1.x); v[5]=f2bf(f1.y); v[6]=f2bf(f1.z); v[7]=f2bf(f1.w);
    *(short8*)(Vb + (size_t)id * 8) = v;
}

// cast weights: Bq = [Wq | Wu | 0], Bv = Wv, Bfc = fc_w  (all bf16, N x K row-major)
__global__ void buildw_k(const float* __restrict__ Wq, const float* __restrict__ Wu,
                         const float* __restrict__ Wv, const float* __restrict__ fcw,
                         short* __restrict__ Bq, short* __restrict__ Bv, short* __restrict__ Bfc) {
    int id = blockIdx.x * 256 + threadIdx.x;
    const int nq = DM * KQ;             // 1024*1088
    const int nv = DM * DM;             // 1024*1024
    const int nf = DM * 2 * DM;         // 1024*2048
    if (id < nq) {
        int n = id / KQ, k = id % KQ;
        float v = (k < 1024) ? Wq[(size_t)n * 1024 + k]
                             : ((k < 1034) ? Wu[n * 10 + (k - 1024)] : 0.f);
        Bq[id] = f2bf(v);
    } else if (id < nq + nv) {
        int j = id - nq;
        Bv[j] = f2bf(Wv[j]);
    } else if (id < nq + nv + nf) {
        int j = id - nq - nv;
        Bfc[j] = f2bf(fcw[j]);
    }
}

// ---------- m97-style MFMA GEMM: C[m][n] = sum_k A[m][k]*B[n][k] ----------
// linear LDS + global_load_lds(16B) staging, XCD-striped block order (nbn==8, nbm%8==0)
// MODE 0: v_s  — bf16 out + transposed bf16 out vT[(b*8+h)*128+hd][v]
// MODE 1: q_s  — bf16 out
// MODE 2: fc   — f32 out = tanh(val + bias)
template <int MODE>
__global__ __launch_bounds__(256) void gemm2_k(
    const short* __restrict__ A, const short* __restrict__ B,
    const float* __restrict__ bias, void* __restrict__ out0,
    short* __restrict__ outT, int M, int N, int K, int out_ld) {
    __shared__ short As[128 * 64];
    __shared__ short Bs[128 * 64];
    const int tid = threadIdx.x;
    const int lane = tid & 63, wave = tid >> 6;
    const int g = lane >> 4, c = lane & 15;
    const int nbm = M >> 7;
    const int x = blockIdx.x & 7, j = blockIdx.x >> 3;
    const int bm = x * (nbm >> 3) + (j >> 3);
    const int bn = j & 7;
    const int wr = wave >> 1, wc = wave & 1;

    const int srow = lane >> 3, scol = (lane & 7) * 8;
    const short* ag = A + (size_t)(bm * 128 + wave * 32 + srow) * K + scol;
    const short* bg = B + (size_t)(bn * 128 + wave * 32 + srow) * K + scol;

    f32x4 acc[4][4] = {};
    for (int k0 = 0; k0 < K; k0 += 64) {
#pragma unroll
        for (int ch = 0; ch < 4; ++ch) {
            gld16(ag + (size_t)(ch * 8) * K + k0, As + (wave * 32 + ch * 8) * 64);
            gld16(bg + (size_t)(ch * 8) * K + k0, Bs + (wave * 32 + ch * 8) * 64);
        }
        __syncthreads();
#pragma unroll
        for (int ks = 0; ks < 2; ++ks) {
            short8 af[4], bfr[4];
#pragma unroll
            for (int mi = 0; mi < 4; ++mi) af[mi] = *(const short8*)(As + (wr * 64 + mi * 16 + c) * 64 + ks * 32 + g * 8);
#pragma unroll
            for (int ni = 0; ni < 4; ++ni) bfr[ni] = *(const short8*)(Bs + (wc * 64 + ni * 16 + c) * 64 + ks * 32 + g * 8);
#pragma unroll
            for (int mi = 0; mi < 4; ++mi)
#pragma unroll
                for (int ni = 0; ni < 4; ++ni)
                    acc[mi][ni] = __builtin_amdgcn_mfma_f32_16x16x32_bf16(af[mi], bfr[ni], acc[mi][ni], 0, 0, 0);
        }
        __syncthreads();
    }

    const int m0 = bm * 128 + wr * 64, n0 = bn * 128 + wc * 64;
#pragma unroll
    for (int ni = 0; ni < 4; ++ni) {
        int n = n0 + ni * 16 + c;
        float bn_ = bias[n];
#pragma unroll
        for (int mi = 0; mi < 4; ++mi) {
            int mb = m0 + mi * 16 + 4 * g;
            f32x4 v = acc[mi][ni];
            if constexpr (MODE == 2) {
                float* o = (float*)out0;
#pragma unroll
                for (int r = 0; r < 4; ++r)
                    o[(size_t)(mb + r) * out_ld + n] = tanhf(v[r] + bn_);
            } else {
                short* o = (short*)out0;
                short4v pk;
#pragma unroll
                for (int r = 0; r < 4; ++r) {
                    pk[r] = f2bf(v[r] + bn_);
                    o[(size_t)(mb + r) * out_ld + n] = pk[r];
                }
                if constexpr (MODE == 0) {
                    int h = n >> 7, hd = n & 127;
                    int bb = mb >> 11, vv = mb & 2047;
                    *(short4v*)(outT + ((size_t)((bb * NH + h) * DH + hd)) * VL + vv) = pk;
                }
            }
        }
    }
}

// ---------- rowsum kernel ----------
// Per (b,h): S = q_s_head (512x128) @ v_s_head^T (128x2048); accumulate
// partial row sums of sigmoid(S/sqrt(128)) only (no p materialization).
__global__ __launch_bounds__(256) void rowsum_k(
    const short* __restrict__ qs, const short* __restrict__ vs,
    float* __restrict__ rsum_part) {
    __shared__ short As[128 * 64];
    __shared__ short Bs[128 * 64];
    const int blk = blockIdx.x;
    const int xr = blk & 7, t = blk >> 3;
    const int bn = t & 15;          // 16 col tiles of 128 v
    const int bm = (t >> 4) & 3;    // 4 row tiles of 128 q
    const int bh = ((t >> 6) << 3) | xr;
    const int h = bh & 7, b = bh >> 3;

    const int tid = threadIdx.x;
    const int lane = tid & 63, wave = tid >> 6;
    const int g = lane >> 4, c = lane & 15;
    const int wr = wave >> 1, wc = wave & 1;
    const float sc = 0.08838834764831845f;   // 1/sqrt(128)

    const int srow = lane >> 3, scol = (lane & 7) * 8;
    const short* ag = qs + (size_t)(b * QL + bm * 128 + wave * 32 + srow) * DM + h * DH + scol;
    const short* bg = vs + (size_t)(b * VL + bn * 128 + wave * 32 + srow) * DM + h * DH + scol;

    f32x4 acc[4][4] = {};
    for (int k0 = 0; k0 < DH; k0 += 64) {
#pragma unroll
        for (int ch = 0; ch < 4; ++ch) {
            gld16(ag + (size_t)(ch * 8) * DM + k0, As + (wave * 32 + ch * 8) * 64);
            gld16(bg + (size_t)(ch * 8) * DM + k0, Bs + (wave * 32 + ch * 8) * 64);
        }
        __syncthreads();
#pragma unroll
        for (int ks = 0; ks < 2; ++ks) {
            short8 af[4], bfr[4];
#pragma unroll
            for (int mi = 0; mi < 4; ++mi) af[mi] = *(const short8*)(As + (wr * 64 + mi * 16 + c) * 64 + ks * 32 + g * 8);
#pragma unroll
            for (int ni = 0; ni < 4; ++ni) bfr[ni] = *(const short8*)(Bs + (wc * 64 + ni * 16 + c) * 64 + ks * 32 + g * 8);
#pragma unroll
            for (int mi = 0; mi < 4; ++mi)
#pragma unroll
                for (int ni = 0; ni < 4; ++ni)
                    acc[mi][ni] = __builtin_amdgcn_mfma_f32_16x16x32_bf16(af[mi], bfr[ni], acc[mi][ni], 0, 0, 0);
        }
        __syncthreads();
    }

    float psum[4][4];
#pragma unroll
    for (int mi = 0; mi < 4; ++mi)
#pragma unroll
        for (int r = 0; r < 4; ++r) psum[mi][r] = 0.f;

    const int m0 = bm * 128 + wr * 64;
#pragma unroll
    for (int ni = 0; ni < 4; ++ni) {
#pragma unroll
        for (int mi = 0; mi < 4; ++mi) {
            f32x4 v = acc[mi][ni];
#pragma unroll
            for (int r = 0; r < 4; ++r)
                psum[mi][r] += __builtin_amdgcn_rcpf(1.f + __expf(-v[r] * sc));
        }
    }
#pragma unroll
    for (int off = 1; off < 16; off <<= 1)
#pragma unroll
        for (int mi = 0; mi < 4; ++mi)
#pragma unroll
            for (int r = 0; r < 4; ++r) psum[mi][r] += __shfl_xor(psum[mi][r], off);
    if (c == 0) {
#pragma unroll
        for (int mi = 0; mi < 4; ++mi)
#pragma unroll
            for (int r = 0; r < 4; ++r) {
                int q = m0 + mi * 16 + 4 * g + r;
                rsum_part[(size_t)(bh * QL + q) * 32 + bn * 2 + wc] = psum[mi][r];
            }
    }
}

// ---------- fused attention kernel ----------
// Block = (bh, 64-q tile); 4 waves x 16 q-rows. Walks VL in 64-chunks:
// stage v_s chunk + vsT chunk in padded LDS; QK MFMA -> sigmoid*inv ->
// nontemporal align write + P->LDS roundtrip -> PV MFMA. Single V pass.
__global__ __launch_bounds__(256) void fat_k(
    const short* __restrict__ qs, const short* __restrict__ vs,
    const short* __restrict__ vsT, const float* __restrict__ rsum_part,
    float* __restrict__ align_out, short* __restrict__ comb) {
    __shared__ short Vs[64][136];
    __shared__ short Vt[128][72];
    __shared__ short Pl[4][16][72];
    __shared__ float rsl[64];

    const int blk = blockIdx.x;          // 512; phys%8 groups bh on one XCD
    const int xr = blk & 7, t = blk >> 3;
    const int qt = t & 7;
    const int bh = ((t >> 3) << 3) | xr;
    const int h = bh & 7, b = bh >> 3;
    const int q0 = qt * 64;

    const int tid = threadIdx.x, wave = tid >> 6, lane = tid & 63;
    const int g = lane >> 4, c = lane & 15;
    const float sc = 0.08838834764831845f;      // 1/sqrt(128)

    // fused row-sum reduce -> inv
    if (tid < 64) {
        const float* p = rsum_part + (size_t)(bh * QL + q0 + tid) * 32;
        float s = 0.f;
#pragma unroll
        for (int jj = 0; jj < 32; ++jj) s += p[jj];
        rsl[tid] = __builtin_amdgcn_rcpf(s);
    }
    __syncthreads();

    float invr[4];
#pragma unroll
    for (int r = 0; r < 4; ++r) invr[r] = rsl[wave * 16 + 4 * g + r];

    // Q fragments from global (one-time, 16 rows x 128 d per wave)
    short8 qa[4];
    const short* qb = qs + ((size_t)(b * QL + q0 + wave * 16 + c)) * DM + h * DH + g * 8;
#pragma unroll
    for (int ks = 0; ks < 4; ++ks) qa[ks] = *(const short8*)(qb + ks * 32);

    // staging bases
    const int vsrow = tid >> 2, vscq = (tid & 3) * 32;
    const short* vsg = vs + ((size_t)(b * VL + vsrow)) * DM + h * DH + vscq;
    const int vtrow = tid >> 1, vtcq = (tid & 1) * 32;
    const short* vtg = vsT + ((size_t)(bh * DH + vtrow)) * VL + vtcq;

    float* ao = align_out + ((size_t)((h * NB + b) * QL + q0 + wave * 16)) * VL;

    f32x4 ctx[8] = {};
    for (int v0 = 0; v0 < VL; v0 += 64) {
        // stage v_s chunk (64 x 128) and vsT chunk (128 x 64), padded
#pragma unroll
        for (int i = 0; i < 4; ++i)
            *(short8*)&Vs[vsrow][vscq + i * 8] = *(const short8*)(vsg + (size_t)v0 * DM + i * 8);
#pragma unroll
        for (int i = 0; i < 4; ++i)
            *(short8*)&Vt[vtrow][vtcq + i * 8] = *(const short8*)(vtg + v0 + i * 8);
        __syncthreads();

        // QK: S chunk 16q x 64v per wave
#pragma unroll
        for (int ni = 0; ni < 4; ++ni) {
            f32x4 s = {0.f, 0.f, 0.f, 0.f};
#pragma unroll
            for (int ks = 0; ks < 4; ++ks)
                s = __builtin_amdgcn_mfma_f32_16x16x32_bf16(qa[ks], *(const short8*)&Vs[ni * 16 + c][ks * 32 + g * 8], s, 0, 0, 0);
#pragma unroll
            for (int r = 0; r < 4; ++r) {
                float pn = __builtin_amdgcn_rcpf(1.f + __expf(-s[r] * sc)) * invr[r];
                __builtin_nontemporal_store(pn, &ao[(size_t)(4 * g + r) * VL + v0 + ni * 16 + c]);
                Pl[wave][4 * g + r][ni * 16 + c] = f2bf(pn);
            }
        }
        // PV: ctx += P_chunk @ Vt_chunk^T
        short8 pa0 = *(const short8*)&Pl[wave][c][g * 8];
        short8 pa1 = *(const short8*)&Pl[wave][c][32 + g * 8];
#pragma unroll
        for (int df = 0; df < 8; ++df) {
            ctx[df] = __builtin_amdgcn_mfma_f32_16x16x32_bf16(pa0, *(const short8*)&Vt[df * 16 + c][g * 8], ctx[df], 0, 0, 0);
            ctx[df] = __builtin_amdgcn_mfma_f32_16x16x32_bf16(pa1, *(const short8*)&Vt[df * 16 + c][32 + g * 8], ctx[df], 0, 0, 0);
        }
        __syncthreads();
    }

    // write context (bf16) into combined[:, 0:1024]
#pragma unroll
    for (int df = 0; df < 8; ++df)
#pragma unroll
        for (int r = 0; r < 4; ++r)
            comb[((size_t)(b * QL + q0 + wave * 16 + 4 * g + r)) * (2 * DM) + h * DH + df * 16 + c] = f2bf(ctx[df][r]);
}

// ---------- launch ----------
extern "C" void kernel_launch(void* const* d_in, const int* in_sizes, int n_in,
                              void* d_out, int out_size, void* d_ws, size_t ws_size,
                              hipStream_t stream) {
    (void)in_sizes; (void)n_in; (void)out_size; (void)ws_size;
    const float* Q    = (const float*)d_in[0];
    const float* V    = (const float*)d_in[1];
    const float* la   = (const float*)d_in[2];
    const float* cw   = (const float*)d_in[3];
    const float* cb   = (const float*)d_in[4];
    const float* Wq   = (const float*)d_in[5];
    const float* bq   = (const float*)d_in[6];
    const float* Wv   = (const float*)d_in[7];
    const float* bv   = (const float*)d_in[8];
    const float* Wu   = (const float*)d_in[9];
    const float* bu   = (const float*)d_in[10];
    const float* bias = (const float*)d_in[11];
    const float* fcw  = (const float*)d_in[12];
    const float* fcb  = (const float*)d_in[13];

    float* out = (float*)d_out;
    float* align_out = out + (size_t)NB * QL * DM;

    // ws layout with lifetime overlap: R0 (32MB) holds Vb first, then Aq+comb+cbias
    char* w = (char*)d_ws;
    char* R0 = w;                        w += (size_t)33554432;  // 32 MB
    short* Vb    = (short*)R0;                                   // 16384x1024 bf16 (dead after v_s)
    short* Aq    = (short*)R0;                                   // 4096x1088 bf16 = 8,912,896 B
    short* comb  = (short*)(R0 + 8912896);                       // 4096x2048 bf16 = 16,777,216 B
    float* cbias = (float*)(R0 + 8912896 + 16777216);            // 4 KB
    short* Bq   = (short*)w; w += (size_t)1024 * KQ * 2;         // 2.2 MB
    short* Bvw  = (short*)w; w += (size_t)1024 * 1024 * 2;       // 2 MB
    short* Bfc  = (short*)w; w += (size_t)1024 * 2048 * 2;       // 4 MB
    short* vsb  = (short*)w; w += (size_t)16384 * 1024 * 2;      // 32 MB
    short* vsT  = (short*)w; w += (size_t)16384 * 1024 * 2;      // 32 MB
    short* qsb  = (short*)w; w += (size_t)4096 * 1024 * 2;       // 8 MB
    float* rsum_part = (float*)w; w += (size_t)32768 * 32 * 4;   // 4 MB

    // phase 1: V path (Vb alive)
    castv_k<<<8192, 256, 0, stream>>>(V, Vb);
    {
        int total = 1024 * KQ + 1024 * 1024 + 1024 * 2048;
        buildw_k<<<(total + 255) / 256, 256, 0, stream>>>(Wq, Wu, Wv, fcw, Bq, Bvw, Bfc);
    }
    gemm2_k<0><<<1024, 256, 0, stream>>>(Vb, Bvw, bv, vsb, vsT, 16384, 1024, 1024, 1024);
    // phase 2: Q path (Aq/comb overwrite Vb region)
    cbias_k<<<4, 256, 0, stream>>>(bq, bu, bias, cbias);
    conv_prep_k<<<16, 256, 0, stream>>>(la, cw, cb, Aq);
    castq_k<<<2048, 256, 0, stream>>>(Q, Aq, comb);
    gemm2_k<1><<<256, 256, 0, stream>>>(Aq, Bq, cbias, qsb, nullptr, 4096, 1024, KQ, 1024);
    // attention: rowsum pre-pass, then fused QK/sigmoid/align/PV
    rowsum_k<<<4096, 256, 0, stream>>>(qsb, vsb, rsum_part);
    fat_k<<<512, 256, 0, stream>>>(qsb, vsb, vsT, rsum_part, align_out, comb);
    // output = tanh(combined @ fc_w^T + fc_b)
    gemm2_k<2><<<256, 256, 0, stream>>>(comb, Bfc, fcb, out, nullptr, 4096, 1024, 2048, 1024);
}

// Round 7
// 311.361 us; speedup vs baseline: 2.1852x; 1.1424x over previous
//
#include <hip/hip_runtime.h>

// ---------- types ----------
typedef __attribute__((ext_vector_type(8))) short short8;
typedef __attribute__((ext_vector_type(4))) short short4v;
typedef __attribute__((ext_vector_type(4))) float f32x4;

static __device__ __forceinline__ short f2bf(float x) {
    unsigned u = __builtin_bit_cast(unsigned, x);
    unsigned r = (u + 0x7fffu + ((u >> 16) & 1u)) >> 16;
    return (short)r;
}

// async global->LDS, 16B per lane: lds dest = uniform base + lane*16
static __device__ __forceinline__ void gld16(const short* g, short* l) {
    __builtin_amdgcn_global_load_lds((const __attribute__((address_space(1))) void*)g,
                                     (__attribute__((address_space(3))) void*)l, 16, 0, 0);
}

#define QL 512
#define VL 2048
#define DM 1024
#define NH 8
#define DH 128
#define NB 8
#define KQ 1088   // 1024 + 64 (U columns padded)

// ---------- merged prep kernel ----------
// ranges: [0,4) cbias | [4,20) conv | [20,2068) castq | [2068,10260) castv | [10260,26900) buildw
__global__ void prep_k(const float* __restrict__ Q, const float* __restrict__ V,
                       const float* __restrict__ la, const float* __restrict__ cw,
                       const float* __restrict__ cb,
                       const float* __restrict__ Wq, const float* __restrict__ bq,
                       const float* __restrict__ Wv, const float* __restrict__ Wu,
                       const float* __restrict__ bu, const float* __restrict__ bias,
                       const float* __restrict__ fcw,
                       float* __restrict__ cbias, short* __restrict__ Aq,
                       short* __restrict__ comb, short* __restrict__ Vb,
                       short* __restrict__ Bq, short* __restrict__ Bv,
                       short* __restrict__ Bfc) {
    const int blk = blockIdx.x, tid = threadIdx.x;
    if (blk < 4) {
        int i = blk * 256 + tid;
        if (i < DM) cbias[i] = bq[i] + bu[i] + bias[i];
    } else if (blk < 20) {
        int m = (blk - 4) * 256 + tid;
        if (m >= NB * QL) return;
        int b = m >> 9, t = m & 511;
        const float* l = la + b * QL;
        float lm = (t > 0)      ? l[t - 1] : 0.f;
        float l0 = l[t];
        float lp = (t < QL - 1) ? l[t + 1] : 0.f;
        short* row = Aq + (size_t)m * KQ + 1024;
#pragma unroll
        for (int k = 0; k < 10; ++k)
            row[k] = f2bf(cb[k] + lm * cw[k * 3 + 0] + l0 * cw[k * 3 + 1] + lp * cw[k * 3 + 2]);
        for (int k = 10; k < 64; ++k) row[k] = 0;
    } else if (blk < 2068) {
        int id = (blk - 20) * 256 + tid;
        int m = id >> 7, kc = (id & 127) * 8;
        const float* p = Q + (size_t)m * DM + kc;
        float4 f0 = *(const float4*)p;
        float4 f1 = *(const float4*)(p + 4);
        short8 v;
        v[0]=f2bf(f0.x); v[1]=f2bf(f0.y); v[2]=f2bf(f0.z); v[3]=f2bf(f0.w);
        v[4]=f2bf(f1.x); v[5]=f2bf(f1.y); v[6]=f2bf(f1.z); v[7]=f2bf(f1.w);
        *(short8*)(Aq + (size_t)m * KQ + kc) = v;
        *(short8*)(comb + (size_t)m * (2 * DM) + DM + kc) = v;
    } else if (blk < 10260) {
        int id = (blk - 2068) * 256 + tid;
        const float* p = V + (size_t)id * 8;
        float4 f0 = *(const float4*)p;
        float4 f1 = *(const float4*)(p + 4);
        short8 v;
        v[0]=f2bf(f0.x); v[1]=f2bf(f0.y); v[2]=f2bf(f0.z); v[3]=f2bf(f0.w);
        v[4]=f2bf(f1.x); v[5]=f2bf(f1.y); v[6]=f2bf(f1.z); v[7]=f2bf(f1.w);
        *(short8*)(Vb + (size_t)id * 8) = v;
    } else {
        int id = (blk - 10260) * 256 + tid;
        const int nq = DM * KQ;             // 1,114,112
        const int nv = DM * DM;             // 1,048,576
        const int nf = DM * 2 * DM;         // 2,097,152  -> total 4,259,840 = 16640 blocks
        if (id < nq) {
            int n = id / KQ, k = id % KQ;
            float v = (k < 1024) ? Wq[(size_t)n * 1024 + k]
                                 : ((k < 1034) ? Wu[n * 10 + (k - 1024)] : 0.f);
            Bq[id] = f2bf(v);
        } else if (id < nq + nv) {
            int j = id - nq;
            Bv[j] = f2bf(Wv[j]);
        } else if (id < nq + nv + nf) {
            int j = id - nq - nv;
            Bfc[j] = f2bf(fcw[j]);
        }
    }
}

// ---------- m97-style MFMA GEMM: C[m][n] = sum_k A[m][k]*B[n][k] ----------
// linear LDS + global_load_lds(16B) staging, XCD-striped block order (nbn==8, nbm%8==0)
// MODE 0: v_s  — bf16 out + transposed bf16 out vT[(b*8+h)*128+hd][v]
// MODE 1: q_s  — bf16 out
// MODE 2: fc   — f32 out = tanh(val + bias)
template <int MODE>
__global__ __launch_bounds__(256) void gemm2_k(
    const short* __restrict__ A, const short* __restrict__ B,
    const float* __restrict__ bias, void* __restrict__ out0,
    short* __restrict__ outT, int M, int N, int K, int out_ld) {
    __shared__ short As[128 * 64];
    __shared__ short Bs[128 * 64];
    const int tid = threadIdx.x;
    const int lane = tid & 63, wave = tid >> 6;
    const int g = lane >> 4, c = lane & 15;
    const int nbm = M >> 7;
    const int x = blockIdx.x & 7, j = blockIdx.x >> 3;
    const int bm = x * (nbm >> 3) + (j >> 3);
    const int bn = j & 7;
    const int wr = wave >> 1, wc = wave & 1;

    const int srow = lane >> 3, scol = (lane & 7) * 8;
    const short* ag = A + (size_t)(bm * 128 + wave * 32 + srow) * K + scol;
    const short* bg = B + (size_t)(bn * 128 + wave * 32 + srow) * K + scol;

    f32x4 acc[4][4] = {};
    for (int k0 = 0; k0 < K; k0 += 64) {
#pragma unroll
        for (int ch = 0; ch < 4; ++ch) {
            gld16(ag + (size_t)(ch * 8) * K + k0, As + (wave * 32 + ch * 8) * 64);
            gld16(bg + (size_t)(ch * 8) * K + k0, Bs + (wave * 32 + ch * 8) * 64);
        }
        __syncthreads();
#pragma unroll
        for (int ks = 0; ks < 2; ++ks) {
            short8 af[4], bfr[4];
#pragma unroll
            for (int mi = 0; mi < 4; ++mi) af[mi] = *(const short8*)(As + (wr * 64 + mi * 16 + c) * 64 + ks * 32 + g * 8);
#pragma unroll
            for (int ni = 0; ni < 4; ++ni) bfr[ni] = *(const short8*)(Bs + (wc * 64 + ni * 16 + c) * 64 + ks * 32 + g * 8);
#pragma unroll
            for (int mi = 0; mi < 4; ++mi)
#pragma unroll
                for (int ni = 0; ni < 4; ++ni)
                    acc[mi][ni] = __builtin_amdgcn_mfma_f32_16x16x32_bf16(af[mi], bfr[ni], acc[mi][ni], 0, 0, 0);
        }
        __syncthreads();
    }

    const int m0 = bm * 128 + wr * 64, n0 = bn * 128 + wc * 64;
#pragma unroll
    for (int ni = 0; ni < 4; ++ni) {
        int n = n0 + ni * 16 + c;
        float bn_ = bias[n];
#pragma unroll
        for (int mi = 0; mi < 4; ++mi) {
            int mb = m0 + mi * 16 + 4 * g;
            f32x4 v = acc[mi][ni];
            if constexpr (MODE == 2) {
                float* o = (float*)out0;
#pragma unroll
                for (int r = 0; r < 4; ++r)
                    o[(size_t)(mb + r) * out_ld + n] = tanhf(v[r] + bn_);
            } else {
                short* o = (short*)out0;
                short4v pk;
#pragma unroll
                for (int r = 0; r < 4; ++r) {
                    pk[r] = f2bf(v[r] + bn_);
                    o[(size_t)(mb + r) * out_ld + n] = pk[r];
                }
                if constexpr (MODE == 0) {
                    int h = n >> 7, hd = n & 127;
                    int bb = mb >> 11, vv = mb & 2047;
                    *(short4v*)(outT + ((size_t)((bb * NH + h) * DH + hd)) * VL + vv) = pk;
                }
            }
        }
    }
}

// ---------- rowsum kernel ----------
__global__ __launch_bounds__(256) void rowsum_k(
    const short* __restrict__ qs, const short* __restrict__ vs,
    float* __restrict__ rsum_part) {
    __shared__ short As[128 * 64];
    __shared__ short Bs[128 * 64];
    const int blk = blockIdx.x;
    const int xr = blk & 7, t = blk >> 3;
    const int bn = t & 15;
    const int bm = (t >> 4) & 3;
    const int bh = ((t >> 6) << 3) | xr;
    const int h = bh & 7, b = bh >> 3;

    const int tid = threadIdx.x;
    const int lane = tid & 63, wave = tid >> 6;
    const int g = lane >> 4, c = lane & 15;
    const int wr = wave >> 1, wc = wave & 1;
    const float sc = 0.08838834764831845f;   // 1/sqrt(128)

    const int srow = lane >> 3, scol = (lane & 7) * 8;
    const short* ag = qs + (size_t)(b * QL + bm * 128 + wave * 32 + srow) * DM + h * DH + scol;
    const short* bg = vs + (size_t)(b * VL + bn * 128 + wave * 32 + srow) * DM + h * DH + scol;

    f32x4 acc[4][4] = {};
    for (int k0 = 0; k0 < DH; k0 += 64) {
#pragma unroll
        for (int ch = 0; ch < 4; ++ch) {
            gld16(ag + (size_t)(ch * 8) * DM + k0, As + (wave * 32 + ch * 8) * 64);
            gld16(bg + (size_t)(ch * 8) * DM + k0, Bs + (wave * 32 + ch * 8) * 64);
        }
        __syncthreads();
#pragma unroll
        for (int ks = 0; ks < 2; ++ks) {
            short8 af[4], bfr[4];
#pragma unroll
            for (int mi = 0; mi < 4; ++mi) af[mi] = *(const short8*)(As + (wr * 64 + mi * 16 + c) * 64 + ks * 32 + g * 8);
#pragma unroll
            for (int ni = 0; ni < 4; ++ni) bfr[ni] = *(const short8*)(Bs + (wc * 64 + ni * 16 + c) * 64 + ks * 32 + g * 8);
#pragma unroll
            for (int mi = 0; mi < 4; ++mi)
#pragma unroll
                for (int ni = 0; ni < 4; ++ni)
                    acc[mi][ni] = __builtin_amdgcn_mfma_f32_16x16x32_bf16(af[mi], bfr[ni], acc[mi][ni], 0, 0, 0);
        }
        __syncthreads();
    }

    float psum[4][4];
#pragma unroll
    for (int mi = 0; mi < 4; ++mi)
#pragma unroll
        for (int r = 0; r < 4; ++r) psum[mi][r] = 0.f;

    const int m0 = bm * 128 + wr * 64;
#pragma unroll
    for (int ni = 0; ni < 4; ++ni) {
#pragma unroll
        for (int mi = 0; mi < 4; ++mi) {
            f32x4 v = acc[mi][ni];
#pragma unroll
            for (int r = 0; r < 4; ++r)
                psum[mi][r] += __builtin_amdgcn_rcpf(1.f + __expf(-v[r] * sc));
        }
    }
#pragma unroll
    for (int off = 1; off < 16; off <<= 1)
#pragma unroll
        for (int mi = 0; mi < 4; ++mi)
#pragma unroll
            for (int r = 0; r < 4; ++r) psum[mi][r] += __shfl_xor(psum[mi][r], off);
    if (c == 0) {
#pragma unroll
        for (int mi = 0; mi < 4; ++mi)
#pragma unroll
            for (int r = 0; r < 4; ++r) {
                int q = m0 + mi * 16 + 4 * g + r;
                rsum_part[(size_t)(bh * QL + q) * 32 + bn * 2 + wc] = psum[mi][r];
            }
    }
}

// ---------- fused attention kernel, V-split ----------
// Block = (bh, 64-q tile, v-half); 4 waves x 16 q-rows; 16 chunks of 64 v.
// T14 async-stage: issue next chunk's global loads right after barrier.
// Writes normalized align (nontemporal) + partial ctx f32 to ctxp.
__global__ __launch_bounds__(256, 3) void fat2_k(
    const short* __restrict__ qs, const short* __restrict__ vs,
    const short* __restrict__ vsT, const float* __restrict__ rsum_part,
    float* __restrict__ align_out, float* __restrict__ ctxp) {
    __shared__ short Vs[64][136];
    __shared__ short Vt[128][72];
    __shared__ short Pl[4][16][72];
    __shared__ float rsl[64];

    const int blk = blockIdx.x;          // 1024; phys%8 groups bh on one XCD
    const int xr = blk & 7, t = blk >> 3;
    const int vh = t & 1;
    const int qt = (t >> 1) & 7;
    const int bh = ((t >> 4) << 3) | xr;
    const int h = bh & 7, b = bh >> 3;
    const int q0 = qt * 64;
    const int vbeg = vh * 1024;

    const int tid = threadIdx.x, wave = tid >> 6, lane = tid & 63;
    const int g = lane >> 4, c = lane & 15;
    const float sc = 0.08838834764831845f;      // 1/sqrt(128)

    if (tid < 64) {
        const float* p = rsum_part + (size_t)(bh * QL + q0 + tid) * 32;
        float s = 0.f;
#pragma unroll
        for (int jj = 0; jj < 32; ++jj) s += p[jj];
        rsl[tid] = __builtin_amdgcn_rcpf(s);
    }
    __syncthreads();

    float invr[4];
#pragma unroll
    for (int r = 0; r < 4; ++r) invr[r] = rsl[wave * 16 + 4 * g + r];

    // Q fragments (one-time, 16 rows x 128 d per wave)
    short8 qa[4];
    const short* qb = qs + ((size_t)(b * QL + q0 + wave * 16 + c)) * DM + h * DH + g * 8;
#pragma unroll
    for (int ks = 0; ks < 4; ++ks) qa[ks] = *(const short8*)(qb + ks * 32);

    // staging bases
    const int vsrow = tid >> 2, vscq = (tid & 3) * 32;
    const short* vsg = vs + ((size_t)(b * VL + vsrow)) * DM + h * DH + vscq;
    const int vtrow = tid >> 1, vtcq = (tid & 1) * 32;
    const short* vtg = vsT + ((size_t)(bh * DH + vtrow)) * VL + vtcq;

    float* ao = align_out + ((size_t)((h * NB + b) * QL + q0 + wave * 16)) * VL;

    // prologue: load chunk 0 into regs
    short8 pv_s[4], pv_t[4];
#pragma unroll
    for (int i = 0; i < 4; ++i) pv_s[i] = *(const short8*)(vsg + (size_t)vbeg * DM + i * 8);
#pragma unroll
    for (int i = 0; i < 4; ++i) pv_t[i] = *(const short8*)(vtg + vbeg + i * 8);

    f32x4 ctx[8] = {};
    for (int tc = 0; tc < 16; ++tc) {
        const int v0 = vbeg + tc * 64;
        // write staged regs to LDS
#pragma unroll
        for (int i = 0; i < 4; ++i) *(short8*)&Vs[vsrow][vscq + i * 8] = pv_s[i];
#pragma unroll
        for (int i = 0; i < 4; ++i) *(short8*)&Vt[vtrow][vtcq + i * 8] = pv_t[i];
        __syncthreads();
        // T14: issue next chunk's loads early (hide under compute)
        if (tc + 1 < 16) {
            const int v1 = v0 + 64;
#pragma unroll
            for (int i = 0; i < 4; ++i) pv_s[i] = *(const short8*)(vsg + (size_t)v1 * DM + i * 8);
#pragma unroll
            for (int i = 0; i < 4; ++i) pv_t[i] = *(const short8*)(vtg + v1 + i * 8);
        }

        // QK: S chunk 16q x 64v per wave
#pragma unroll
        for (int ni = 0; ni < 4; ++ni) {
            f32x4 s = {0.f, 0.f, 0.f, 0.f};
#pragma unroll
            for (int ks = 0; ks < 4; ++ks)
                s = __builtin_amdgcn_mfma_f32_16x16x32_bf16(qa[ks], *(const short8*)&Vs[ni * 16 + c][ks * 32 + g * 8], s, 0, 0, 0);
#pragma unroll
            for (int r = 0; r < 4; ++r) {
                float pn = __builtin_amdgcn_rcpf(1.f + __expf(-s[r] * sc)) * invr[r];
                __builtin_nontemporal_store(pn, &ao[(size_t)(4 * g + r) * VL + v0 + ni * 16 + c]);
                Pl[wave][4 * g + r][ni * 16 + c] = f2bf(pn);
            }
        }
        // PV: ctx += P_chunk @ Vt_chunk^T
        short8 pa0 = *(const short8*)&Pl[wave][c][g * 8];
        short8 pa1 = *(const short8*)&Pl[wave][c][32 + g * 8];
#pragma unroll
        for (int df = 0; df < 8; ++df) {
            ctx[df] = __builtin_amdgcn_mfma_f32_16x16x32_bf16(pa0, *(const short8*)&Vt[df * 16 + c][g * 8], ctx[df], 0, 0, 0);
            ctx[df] = __builtin_amdgcn_mfma_f32_16x16x32_bf16(pa1, *(const short8*)&Vt[df * 16 + c][32 + g * 8], ctx[df], 0, 0, 0);
        }
        __syncthreads();
    }

    // store partial ctx (f32) to scratch
    float* cp = ctxp + ((size_t)((bh * 8 + qt) * 2 + vh)) * (64 * 128);
#pragma unroll
    for (int df = 0; df < 8; ++df)
#pragma unroll
        for (int r = 0; r < 4; ++r)
            cp[(size_t)(wave * 16 + 4 * g + r) * 128 + df * 16 + c] = ctx[df][r];
}

// ---------- ctx reduce: comb ctx half = bf16(part0 + part1) ----------
__global__ void ctxred_k(const float* __restrict__ ctxp, short* __restrict__ comb) {
    int id = blockIdx.x * 256 + threadIdx.x;   // 524288 ids, 8 elems each
    int d0 = (id & 15) * 8;
    int r  = (id >> 4) & 63;
    int qt = (id >> 10) & 7;
    int bh = id >> 13;
    int h = bh & 7, b = bh >> 3;
    const float* p0 = ctxp + ((size_t)((bh * 8 + qt) * 2)) * 8192 + r * 128 + d0;
    const float* p1 = p0 + 8192;
    short8 o;
#pragma unroll
    for (int jj = 0; jj < 8; ++jj) o[jj] = f2bf(p0[jj] + p1[jj]);
    *(short8*)(comb + ((size_t)(b * QL + qt * 64 + r)) * (2 * DM) + h * DH + d0) = o;
}

// ---------- launch ----------
extern "C" void kernel_launch(void* const* d_in, const int* in_sizes, int n_in,
                              void* d_out, int out_size, void* d_ws, size_t ws_size,
                              hipStream_t stream) {
    (void)in_sizes; (void)n_in; (void)out_size; (void)ws_size;
    const float* Q    = (const float*)d_in[0];
    const float* V    = (const float*)d_in[1];
    const float* la   = (const float*)d_in[2];
    const float* cw   = (const float*)d_in[3];
    const float* cb   = (const float*)d_in[4];
    const float* Wq   = (const float*)d_in[5];
    const float* bq   = (const float*)d_in[6];
    const float* Wv   = (const float*)d_in[7];
    const float* bv   = (const float*)d_in[8];
    const float* Wu   = (const float*)d_in[9];
    const float* bu   = (const float*)d_in[10];
    const float* bias = (const float*)d_in[11];
    const float* fcw  = (const float*)d_in[12];
    const float* fcb  = (const float*)d_in[13];

    float* out = (float*)d_out;
    float* align_out = out + (size_t)NB * QL * DM;

    char* w = (char*)d_ws;
    short* Vb   = (short*)w; w += (size_t)16384 * 1024 * 2;      // 32 MB
    short* Aq   = (short*)w; w += (size_t)4096 * KQ * 2;         // 8.9 MB
    short* comb = (short*)w; w += (size_t)4096 * 2048 * 2;       // 16 MB
    short* Bq   = (short*)w; w += (size_t)1024 * KQ * 2;         // 2.2 MB
    short* Bvw  = (short*)w; w += (size_t)1024 * 1024 * 2;       // 2 MB
    short* Bfc  = (short*)w; w += (size_t)1024 * 2048 * 2;       // 4 MB
    short* vsb  = (short*)w; w += (size_t)16384 * 1024 * 2;      // 32 MB
    short* vsT  = (short*)w; w += (size_t)16384 * 1024 * 2;      // 32 MB
    short* qsb  = (short*)w; w += (size_t)4096 * 1024 * 2;       // 8 MB
    float* rsum_part = (float*)w; w += (size_t)32768 * 32 * 4;   // 4 MB
    float* ctxp = (float*)w; w += (size_t)1024 * 64 * 128 * 4;   // 32 MB
    float* cbias = (float*)w; w += 1024 * 4;

    // all prep in one launch (ranges: cbias|conv|castq|castv|buildw) — 26900 blocks
    prep_k<<<26900, 256, 0, stream>>>(Q, V, la, cw, cb, Wq, bq, Wv, Wu, bu, bias, fcw,
                                      cbias, Aq, comb, Vb, Bq, Bvw, Bfc);
    // v_s = V @ Wv^T + bv  (+ transposed copy per head)
    gemm2_k<0><<<1024, 256, 0, stream>>>(Vb, Bvw, bv, vsb, vsT, 16384, 1024, 1024, 1024);
    // q_s = [Q|U] @ [Wq|Wu]^T + (bq+bu+bias)
    gemm2_k<1><<<256, 256, 0, stream>>>(Aq, Bq, cbias, qsb, nullptr, 4096, 1024, KQ, 1024);
    // attention: rowsum pre-pass, then fused V-split QK/sigmoid/align/PV, then ctx reduce
    rowsum_k<<<4096, 256, 0, stream>>>(qsb, vsb, rsum_part);
    fat2_k<<<1024, 256, 0, stream>>>(qsb, vsb, vsT, rsum_part, align_out, ctxp);
    ctxred_k<<<2048, 256, 0, stream>>>(ctxp, comb);
    // output = tanh(combined @ fc_w^T + fc_b)
    gemm2_k<2><<<256, 256, 0, stream>>>(comb, Bfc, fcb, out, nullptr, 4096, 1024, 2048, 1024);
}